// Round 1
// baseline (253.402 us; speedup 1.0000x reference)
//
#include <hip/hip_runtime.h>
#include <hip/hip_bf16.h>

#define D 96
#define LN_EPS 1e-5f

// ---------------------------------------------------------------------------
// Edge dtype detection: if the edge buffer is int64 (values < 2^31), every
// odd 32-bit word of the first 256 words is zero. For int32 random node ids
// that is (1/50000)^128-improbable. flag=1 -> int64, flag=0 -> int32.
// ---------------------------------------------------------------------------
__global__ __launch_bounds__(256) void k_detect(const unsigned* __restrict__ w,
                                                int* __restrict__ flag) {
    __shared__ int anynz;
    if (threadIdx.x == 0) anynz = 0;
    __syncthreads();
    if ((threadIdx.x & 1) && w[threadIdx.x] != 0) anynz = 1;
    __syncthreads();
    if (threadIdx.x == 0) *flag = (anynz == 0) ? 1 : 0;
}

__device__ __forceinline__ int load_idx(const void* eb, int is64, long long pos) {
    if (is64) return (int)((const long long*)eb)[pos];
    return ((const int*)eb)[pos];
}

__global__ __launch_bounds__(256) void k_zero(int* __restrict__ p, int n) {
    int i = blockIdx.x * 256 + threadIdx.x;
    if (i < n) p[i] = 0;
}

__global__ __launch_bounds__(256) void k_count(const void* __restrict__ eb,
                                               const int* __restrict__ flag,
                                               int* __restrict__ cnt, int E) {
    int e = blockIdx.x * 256 + threadIdx.x;
    if (e >= E) return;
    int is64 = *flag;
    int d = load_idx(eb, is64, (long long)E + e);
    atomicAdd(&cnt[d], 1);
}

// Block-local exclusive scan (256 elems/block), emits block sums.
__global__ __launch_bounds__(256) void k_scan1(const int* __restrict__ cnt,
                                               int* __restrict__ rowptr,
                                               int* __restrict__ bsums, int N) {
    __shared__ int sh[256];
    int tid = threadIdx.x;
    int i = blockIdx.x * 256 + tid;
    int v = (i < N) ? cnt[i] : 0;
    sh[tid] = v;
    __syncthreads();
    for (int off = 1; off < 256; off <<= 1) {
        int t = (tid >= off) ? sh[tid - off] : 0;
        __syncthreads();
        sh[tid] += t;
        __syncthreads();
    }
    if (i < N) rowptr[i] = sh[tid] - v;          // block-local exclusive
    if (tid == 255) bsums[blockIdx.x] = sh[tid]; // block total
}

// Scan the (<=256) block sums in-place to exclusive offsets.
__global__ __launch_bounds__(256) void k_scan2(int* __restrict__ bsums, int nb) {
    __shared__ int sh[256];
    int tid = threadIdx.x;
    int v = (tid < nb) ? bsums[tid] : 0;
    sh[tid] = v;
    __syncthreads();
    for (int off = 1; off < 256; off <<= 1) {
        int t = (tid >= off) ? sh[tid - off] : 0;
        __syncthreads();
        sh[tid] += t;
        __syncthreads();
    }
    if (tid < nb) bsums[tid] = sh[tid] - v;
}

__global__ __launch_bounds__(256) void k_scan3(int* __restrict__ rowptr,
                                               const int* __restrict__ bsums,
                                               int N, int E) {
    int i = blockIdx.x * 256 + threadIdx.x;
    if (i < N) rowptr[i] += bsums[i >> 8];
    if (blockIdx.x == 0 && threadIdx.x == 0) rowptr[N] = E;
}

// cursor = rowptr copy; dis = rsqrt(deg) with deg = cnt + 1 (self-loop).
__global__ __launch_bounds__(256) void k_prep(const int* __restrict__ rowptr,
                                              const int* __restrict__ cnt,
                                              int* __restrict__ cursor,
                                              float* __restrict__ dis, int N) {
    int i = blockIdx.x * 256 + threadIdx.x;
    if (i >= N) return;
    cursor[i] = rowptr[i];
    dis[i] = rsqrtf((float)(cnt[i] + 1));
}

__global__ __launch_bounds__(256) void k_fill(const void* __restrict__ eb,
                                              const int* __restrict__ flag,
                                              const float* __restrict__ dis,
                                              int* __restrict__ cursor,
                                              int* __restrict__ csr_src,
                                              float* __restrict__ csr_norm, int E) {
    int e = blockIdx.x * 256 + threadIdx.x;
    if (e >= E) return;
    int is64 = *flag;
    int s = load_idx(eb, is64, e);
    int d = load_idx(eb, is64, (long long)E + e);
    float nr = dis[s] * dis[d];
    int pos = atomicAdd(&cursor[d], 1);
    csr_src[pos] = s;
    csr_norm[pos] = nr;
}

// ---------------------------------------------------------------------------
// GEMM: H[N,96] = X[N,96] @ W[96,96], f32 VALU (no fp32 MFMA on CDNA4).
// 64 rows per block; W + x-tile staged in LDS; 24 accumulators/thread.
// ---------------------------------------------------------------------------
__global__ __launch_bounds__(256) void k_gemm96(const float* __restrict__ X,
                                                const float* __restrict__ W,
                                                float* __restrict__ H, int N) {
    __shared__ float ws[96][96];  // 36864 B
    __shared__ float xs[64][96];  // 24576 B
    int t = threadIdx.x;

    const float4* W4 = (const float4*)W;
    float4* ws4 = (float4*)&ws[0][0];
    #pragma unroll
    for (int k = 0; k < 9; ++k) ws4[t + k * 256] = W4[t + k * 256];

    int row0 = blockIdx.x * 64;
    const float4* X4 = (const float4*)X;
    float4* xs4 = (float4*)&xs[0][0];
    #pragma unroll
    for (int k = 0; k < 6; ++k) {
        int idx = t + k * 256;      // < 1536 = 64*24
        int r = idx / 24;
        int gr = row0 + r;
        float4 v = make_float4(0.f, 0.f, 0.f, 0.f);
        if (gr < N) v = X4[(size_t)gr * 24 + (idx % 24)];
        xs4[idx] = v;
    }
    __syncthreads();

    int c = t & 31;
    int r0 = (t >> 5) * 8;
    float acc[8][3];
    #pragma unroll
    for (int r = 0; r < 8; ++r) { acc[r][0] = 0.f; acc[r][1] = 0.f; acc[r][2] = 0.f; }

    for (int k = 0; k < 96; ++k) {
        float w0 = ws[k][c], w1 = ws[k][c + 32], w2 = ws[k][c + 64];
        #pragma unroll
        for (int r = 0; r < 8; ++r) {
            float xv = xs[r0 + r][k];
            acc[r][0] = fmaf(xv, w0, acc[r][0]);
            acc[r][1] = fmaf(xv, w1, acc[r][1]);
            acc[r][2] = fmaf(xv, w2, acc[r][2]);
        }
    }
    #pragma unroll
    for (int r = 0; r < 8; ++r) {
        int gr = row0 + r0 + r;
        if (gr < N) {
            float* o = H + (size_t)gr * D;
            o[c] = acc[r][0];
            o[c + 32] = acc[r][1];
            o[c + 64] = acc[r][2];
        }
    }
}

// ---------------------------------------------------------------------------
// Fused aggregate + bias + tanh + LayerNorm + affine.
// One 32-lane group per node; lane owns features {l, l+32, l+64}.
// Gathers are fully coalesced 128B per 32-lane group.
// ---------------------------------------------------------------------------
__global__ __launch_bounds__(256) void k_agg_ln(const float* __restrict__ h,
                                                const int* __restrict__ rowptr,
                                                const int* __restrict__ csr_src,
                                                const float* __restrict__ csr_norm,
                                                const float* __restrict__ dis,
                                                const float* __restrict__ b,
                                                const float* __restrict__ g,
                                                const float* __restrict__ be,
                                                float* __restrict__ out, int N) {
    int node = blockIdx.x * 8 + (threadIdx.x >> 5);
    int lane = threadIdx.x & 31;
    if (node >= N) return;

    float di = dis[node];
    float selfn = di * di;
    const float* hp0 = h + (size_t)node * D;
    float a0 = selfn * hp0[lane];
    float a1 = selfn * hp0[lane + 32];
    float a2 = selfn * hp0[lane + 64];

    int beg = rowptr[node], end = rowptr[node + 1];
    for (int base = beg; base < end; base += 32) {
        int e = base + lane;
        int s = 0;
        float nr = 0.f;
        if (e < end) { s = csr_src[e]; nr = csr_norm[e]; }
        int cnt = end - base;
        if (cnt >= 32) {
            #pragma unroll
            for (int j = 0; j < 32; ++j) {
                int ss = __shfl(s, j, 32);
                float nn = __shfl(nr, j, 32);
                const float* hp = h + (size_t)ss * D;
                a0 = fmaf(nn, hp[lane], a0);
                a1 = fmaf(nn, hp[lane + 32], a1);
                a2 = fmaf(nn, hp[lane + 64], a2);
            }
        } else {
            for (int j = 0; j < cnt; ++j) {
                int ss = __shfl(s, j, 32);
                float nn = __shfl(nr, j, 32);
                const float* hp = h + (size_t)ss * D;
                a0 = fmaf(nn, hp[lane], a0);
                a1 = fmaf(nn, hp[lane + 32], a1);
                a2 = fmaf(nn, hp[lane + 64], a2);
            }
        }
    }

    a0 = tanhf(a0 + b[lane]);
    a1 = tanhf(a1 + b[lane + 32]);
    a2 = tanhf(a2 + b[lane + 64]);

    float s1 = a0 + a1 + a2;
    float s2 = a0 * a0 + a1 * a1 + a2 * a2;
    #pragma unroll
    for (int off = 16; off >= 1; off >>= 1) {
        s1 += __shfl_xor(s1, off, 32);
        s2 += __shfl_xor(s2, off, 32);
    }
    float mu = s1 * (1.f / 96.f);
    float var = s2 * (1.f / 96.f) - mu * mu;
    float inv = rsqrtf(var + LN_EPS);

    float* o = out + (size_t)node * D;
    o[lane]      = (a0 - mu) * inv * g[lane]      + be[lane];
    o[lane + 32] = (a1 - mu) * inv * g[lane + 32] + be[lane + 32];
    o[lane + 64] = (a2 - mu) * inv * g[lane + 64] + be[lane + 64];
}

// ---------------------------------------------------------------------------
extern "C" void kernel_launch(void* const* d_in, const int* in_sizes, int n_in,
                              void* d_out, int out_size, void* d_ws, size_t ws_size,
                              hipStream_t stream) {
    const float* x  = (const float*)d_in[0];
    const void*  eb = d_in[1];
    const float* W0 = (const float*)d_in[2];
    const float* b0 = (const float*)d_in[3];
    const float* g0 = (const float*)d_in[4];
    const float* be0 = (const float*)d_in[5];
    const float* W1 = (const float*)d_in[6];
    const float* b1 = (const float*)d_in[7];
    const float* g1 = (const float*)d_in[8];
    const float* be1 = (const float*)d_in[9];

    const int N = in_sizes[0] / D;
    const int E = in_sizes[1] / 2;

    auto al = [](size_t v) { return (v + 255) & ~(size_t)255; };
    char* w = (char*)d_ws;
    size_t off = 0;
    int* flag = (int*)(w + off);        off = al(off + 4);
    int* cnt = (int*)(w + off);         off = al(off + (size_t)N * 4);
    int* rowptr = (int*)(w + off);      off = al(off + (size_t)(N + 1) * 4);
    int* bsums = (int*)(w + off);       off = al(off + 256 * 4);
    int* cursor = (int*)(w + off);      off = al(off + (size_t)N * 4);
    float* dis = (float*)(w + off);     off = al(off + (size_t)N * 4);
    int* csr_src = (int*)(w + off);     off = al(off + (size_t)E * 4);
    float* csr_norm = (float*)(w + off); off = al(off + (size_t)E * 4);
    float* hA = (float*)(w + off);      off = al(off + (size_t)N * D * 4);
    float* outf = (float*)d_out;

    const int nbN = (N + 255) / 256;
    const int nbE = (E + 255) / 256;
    const int nbG = (N + 63) / 64;
    const int nbA = (N + 7) / 8;

    k_detect<<<1, 256, 0, stream>>>((const unsigned*)eb, flag);
    k_zero<<<nbN, 256, 0, stream>>>(cnt, N);
    k_count<<<nbE, 256, 0, stream>>>(eb, flag, cnt, E);
    k_scan1<<<nbN, 256, 0, stream>>>(cnt, rowptr, bsums, N);
    k_scan2<<<1, 256, 0, stream>>>(bsums, nbN);
    k_scan3<<<nbN, 256, 0, stream>>>(rowptr, bsums, N, E);
    k_prep<<<nbN, 256, 0, stream>>>(rowptr, cnt, cursor, dis, N);
    k_fill<<<nbE, 256, 0, stream>>>(eb, flag, dis, cursor, csr_src, csr_norm, E);

    // Layer 1: GEMM -> hA ; aggregate+tanh+LN -> d_out (scratch reuse)
    k_gemm96<<<nbG, 256, 0, stream>>>(x, W0, hA, N);
    k_agg_ln<<<nbA, 256, 0, stream>>>(hA, rowptr, csr_src, csr_norm, dis,
                                      b0, g0, be0, outf, N);
    // Layer 2: GEMM (reads d_out) -> hA ; aggregate -> d_out (final)
    k_gemm96<<<nbG, 256, 0, stream>>>(outf, W1, hA, N);
    k_agg_ln<<<nbA, 256, 0, stream>>>(hA, rowptr, csr_src, csr_norm, dis,
                                      b1, g1, be1, outf, N);
}

// Round 2
// 243.684 us; speedup vs baseline: 1.0399x; 1.0399x over previous
//
#include <hip/hip_runtime.h>
#include <hip/hip_bf16.h>

#define D 96
#define LN_EPS 1e-5f

typedef unsigned short ushort_t;

__device__ __forceinline__ ushort_t f2bf(float f) {
    unsigned u = __float_as_uint(f);
    u += 0x7FFF + ((u >> 16) & 1);          // round-to-nearest-even
    return (ushort_t)(u >> 16);
}
__device__ __forceinline__ float bf2f(ushort_t s) {
    return __uint_as_float((unsigned)s << 16);
}

// ---------------------------------------------------------------------------
// Edge dtype detection: if the edge buffer is int64 (values < 2^31), every
// odd 32-bit word of the first 256 words is zero. flag=1 -> int64, 0 -> int32.
// ---------------------------------------------------------------------------
__global__ __launch_bounds__(256) void k_detect(const unsigned* __restrict__ w,
                                                int* __restrict__ flag) {
    __shared__ int anynz;
    if (threadIdx.x == 0) anynz = 0;
    __syncthreads();
    if ((threadIdx.x & 1) && w[threadIdx.x] != 0) anynz = 1;
    __syncthreads();
    if (threadIdx.x == 0) *flag = (anynz == 0) ? 1 : 0;
}

__device__ __forceinline__ int load_idx(const void* eb, int is64, long long pos) {
    if (is64) return (int)((const long long*)eb)[pos];
    return ((const int*)eb)[pos];
}

__global__ __launch_bounds__(256) void k_count(const void* __restrict__ eb,
                                               const int* __restrict__ flag,
                                               int* __restrict__ cnt, int E) {
    int e = blockIdx.x * 256 + threadIdx.x;
    if (e >= E) return;
    int is64 = *flag;
    int d = load_idx(eb, is64, (long long)E + e);
    atomicAdd(&cnt[d], 1);
}

// Block-local exclusive scan (256 elems/block), emits block sums.
__global__ __launch_bounds__(256) void k_scan1(const int* __restrict__ cnt,
                                               int* __restrict__ rowptr,
                                               int* __restrict__ bsums, int N) {
    __shared__ int sh[256];
    int tid = threadIdx.x;
    int i = blockIdx.x * 256 + tid;
    int v = (i < N) ? cnt[i] : 0;
    sh[tid] = v;
    __syncthreads();
    for (int off = 1; off < 256; off <<= 1) {
        int t = (tid >= off) ? sh[tid - off] : 0;
        __syncthreads();
        sh[tid] += t;
        __syncthreads();
    }
    if (i < N) rowptr[i] = sh[tid] - v;
    if (tid == 255) bsums[blockIdx.x] = sh[tid];
}

__global__ __launch_bounds__(256) void k_scan2(int* __restrict__ bsums, int nb) {
    __shared__ int sh[256];
    int tid = threadIdx.x;
    int v = (tid < nb) ? bsums[tid] : 0;
    sh[tid] = v;
    __syncthreads();
    for (int off = 1; off < 256; off <<= 1) {
        int t = (tid >= off) ? sh[tid - off] : 0;
        __syncthreads();
        sh[tid] += t;
        __syncthreads();
    }
    if (tid < nb) bsums[tid] = sh[tid] - v;
}

// Finalize rowptr, init cursor, compute dis = rsqrt(deg+1).
__global__ __launch_bounds__(256) void k_scan3(int* __restrict__ rowptr,
                                               const int* __restrict__ bsums,
                                               const int* __restrict__ cnt,
                                               int* __restrict__ cursor,
                                               float* __restrict__ dis,
                                               int N, int E) {
    int i = blockIdx.x * 256 + threadIdx.x;
    if (i < N) {
        int v = rowptr[i] + bsums[i >> 8];
        rowptr[i] = v;
        cursor[i] = v;
        dis[i] = rsqrtf((float)(cnt[i] + 1));
    }
    if (blockIdx.x == 0 && threadIdx.x == 0) rowptr[N] = E;
}

// CSR fill: src only (norm factored out entirely).
__global__ __launch_bounds__(256) void k_fill(const void* __restrict__ eb,
                                              const int* __restrict__ flag,
                                              int* __restrict__ cursor,
                                              int* __restrict__ csr_src, int E) {
    int e = blockIdx.x * 256 + threadIdx.x;
    if (e >= E) return;
    int is64 = *flag;
    int s = load_idx(eb, is64, e);
    int d = load_idx(eb, is64, (long long)E + e);
    int pos = atomicAdd(&cursor[d], 1);
    csr_src[pos] = s;
}

// ---------------------------------------------------------------------------
// GEMM: Hs[N,96] = bf16( dis[row] * (X[N,96] @ W[96,96]) ), f32 VALU compute.
// ---------------------------------------------------------------------------
__global__ __launch_bounds__(256) void k_gemm96(const float* __restrict__ X,
                                                const float* __restrict__ W,
                                                const float* __restrict__ dis,
                                                ushort_t* __restrict__ Hs, int N) {
    __shared__ float ws[96][96];  // 36864 B
    __shared__ float xs[64][96];  // 24576 B
    int t = threadIdx.x;

    const float4* W4 = (const float4*)W;
    float4* ws4 = (float4*)&ws[0][0];
    #pragma unroll
    for (int k = 0; k < 9; ++k) ws4[t + k * 256] = W4[t + k * 256];

    int row0 = blockIdx.x * 64;
    const float4* X4 = (const float4*)X;
    float4* xs4 = (float4*)&xs[0][0];
    #pragma unroll
    for (int k = 0; k < 6; ++k) {
        int idx = t + k * 256;      // < 1536 = 64*24
        int r = idx / 24;
        int gr = row0 + r;
        float4 v = make_float4(0.f, 0.f, 0.f, 0.f);
        if (gr < N) v = X4[(size_t)gr * 24 + (idx % 24)];
        xs4[idx] = v;
    }
    __syncthreads();

    int c = t & 31;
    int r0 = (t >> 5) * 8;
    float acc[8][3];
    #pragma unroll
    for (int r = 0; r < 8; ++r) { acc[r][0] = 0.f; acc[r][1] = 0.f; acc[r][2] = 0.f; }

    for (int k = 0; k < 96; ++k) {
        float w0 = ws[k][c], w1 = ws[k][c + 32], w2 = ws[k][c + 64];
        #pragma unroll
        for (int r = 0; r < 8; ++r) {
            float xv = xs[r0 + r][k];
            acc[r][0] = fmaf(xv, w0, acc[r][0]);
            acc[r][1] = fmaf(xv, w1, acc[r][1]);
            acc[r][2] = fmaf(xv, w2, acc[r][2]);
        }
    }
    #pragma unroll
    for (int r = 0; r < 8; ++r) {
        int gr = row0 + r0 + r;
        if (gr < N) {
            float dr = dis[gr];
            ushort_t* o = Hs + (size_t)gr * D;
            o[c]      = f2bf(dr * acc[r][0]);
            o[c + 32] = f2bf(dr * acc[r][1]);
            o[c + 64] = f2bf(dr * acc[r][2]);
        }
    }
}

// ---------------------------------------------------------------------------
// Fused aggregate + bias + tanh + LayerNorm + affine.
// a = dis[node] * ( hs[node] + sum_{src} hs[src] ); hs is bf16.
// One 32-lane group per node; lane owns features {l, l+32, l+64}.
// ---------------------------------------------------------------------------
__global__ __launch_bounds__(256) void k_agg_ln(const ushort_t* __restrict__ hs,
                                                const int* __restrict__ rowptr,
                                                const int* __restrict__ csr_src,
                                                const float* __restrict__ dis,
                                                const float* __restrict__ b,
                                                const float* __restrict__ g,
                                                const float* __restrict__ be,
                                                float* __restrict__ out, int N) {
    int node = blockIdx.x * 8 + (threadIdx.x >> 5);
    int lane = threadIdx.x & 31;
    if (node >= N) return;

    const ushort_t* hp0 = hs + (size_t)node * D;
    float a0 = bf2f(hp0[lane]);
    float a1 = bf2f(hp0[lane + 32]);
    float a2 = bf2f(hp0[lane + 64]);

    int beg = rowptr[node], end = rowptr[node + 1];
    for (int base = beg; base < end; base += 32) {
        int e = base + lane;
        int s = (e < end) ? csr_src[e] : 0;
        int cnt = end - base;
        if (cnt >= 32) {
            #pragma unroll
            for (int j = 0; j < 32; ++j) {
                int ss = __shfl(s, j, 32);
                const ushort_t* hp = hs + (size_t)ss * D;
                a0 += bf2f(hp[lane]);
                a1 += bf2f(hp[lane + 32]);
                a2 += bf2f(hp[lane + 64]);
            }
        } else {
            for (int j = 0; j < cnt; ++j) {
                int ss = __shfl(s, j, 32);
                const ushort_t* hp = hs + (size_t)ss * D;
                a0 += bf2f(hp[lane]);
                a1 += bf2f(hp[lane + 32]);
                a2 += bf2f(hp[lane + 64]);
            }
        }
    }

    float dn = dis[node];
    a0 = tanhf(fmaf(dn, a0, b[lane]));
    a1 = tanhf(fmaf(dn, a1, b[lane + 32]));
    a2 = tanhf(fmaf(dn, a2, b[lane + 64]));

    float s1 = a0 + a1 + a2;
    float s2 = a0 * a0 + a1 * a1 + a2 * a2;
    #pragma unroll
    for (int off = 16; off >= 1; off >>= 1) {
        s1 += __shfl_xor(s1, off, 32);
        s2 += __shfl_xor(s2, off, 32);
    }
    float mu = s1 * (1.f / 96.f);
    float var = s2 * (1.f / 96.f) - mu * mu;
    float inv = rsqrtf(var + LN_EPS);

    float* o = out + (size_t)node * D;
    o[lane]      = (a0 - mu) * inv * g[lane]      + be[lane];
    o[lane + 32] = (a1 - mu) * inv * g[lane + 32] + be[lane + 32];
    o[lane + 64] = (a2 - mu) * inv * g[lane + 64] + be[lane + 64];
}

// ---------------------------------------------------------------------------
extern "C" void kernel_launch(void* const* d_in, const int* in_sizes, int n_in,
                              void* d_out, int out_size, void* d_ws, size_t ws_size,
                              hipStream_t stream) {
    const float* x  = (const float*)d_in[0];
    const void*  eb = d_in[1];
    const float* W0 = (const float*)d_in[2];
    const float* b0 = (const float*)d_in[3];
    const float* g0 = (const float*)d_in[4];
    const float* be0 = (const float*)d_in[5];
    const float* W1 = (const float*)d_in[6];
    const float* b1 = (const float*)d_in[7];
    const float* g1 = (const float*)d_in[8];
    const float* be1 = (const float*)d_in[9];

    const int N = in_sizes[0] / D;
    const int E = in_sizes[1] / 2;

    auto al = [](size_t v) { return (v + 255) & ~(size_t)255; };
    char* w = (char*)d_ws;
    size_t off = 0;
    int* flag = (int*)(w + off);        off = al(off + 4);
    int* cnt = (int*)(w + off);         off = al(off + (size_t)N * 4);
    int* rowptr = (int*)(w + off);      off = al(off + (size_t)(N + 1) * 4);
    int* bsums = (int*)(w + off);       off = al(off + 256 * 4);
    int* cursor = (int*)(w + off);      off = al(off + (size_t)N * 4);
    float* dis = (float*)(w + off);     off = al(off + (size_t)N * 4);
    int* csr_src = (int*)(w + off);     off = al(off + (size_t)E * 4);
    ushort_t* hs = (ushort_t*)(w + off); off = al(off + (size_t)N * D * 2);
    float* outf = (float*)d_out;

    const int nbN = (N + 255) / 256;
    const int nbE = (E + 255) / 256;
    const int nbG = (N + 63) / 64;
    const int nbA = (N + 7) / 8;

    k_detect<<<1, 256, 0, stream>>>((const unsigned*)eb, flag);
    hipMemsetAsync(cnt, 0, (size_t)N * 4, stream);
    k_count<<<nbE, 256, 0, stream>>>(eb, flag, cnt, E);
    k_scan1<<<nbN, 256, 0, stream>>>(cnt, rowptr, bsums, N);
    k_scan2<<<1, 256, 0, stream>>>(bsums, nbN);
    k_scan3<<<nbN, 256, 0, stream>>>(rowptr, bsums, cnt, cursor, dis, N, E);
    k_fill<<<nbE, 256, 0, stream>>>(eb, flag, cursor, csr_src, E);

    // Layer 1: GEMM (dis-scaled, bf16) -> hs ; aggregate+tanh+LN -> d_out
    k_gemm96<<<nbG, 256, 0, stream>>>(x, W0, dis, hs, N);
    k_agg_ln<<<nbA, 256, 0, stream>>>(hs, rowptr, csr_src, dis, b0, g0, be0, outf, N);
    // Layer 2: GEMM (reads d_out) -> hs ; aggregate -> d_out (final)
    k_gemm96<<<nbG, 256, 0, stream>>>(outf, W1, dis, hs, N);
    k_agg_ln<<<nbA, 256, 0, stream>>>(hs, rowptr, csr_src, dis, b1, g1, be1, outf, N);
}

// Round 3
// 193.568 us; speedup vs baseline: 1.3091x; 1.2589x over previous
//
#include <hip/hip_runtime.h>
#include <hip/hip_bf16.h>

#define D 96
#define LN_EPS 1e-5f
#define CHUNK 4096   // edges per partition block

typedef unsigned short ushort_t;

__device__ __forceinline__ ushort_t f2bf(float f) {
    unsigned u = __float_as_uint(f);
    u += 0x7FFF + ((u >> 16) & 1);          // round-to-nearest-even
    return (ushort_t)(u >> 16);
}
__device__ __forceinline__ float bf2f(ushort_t s) {
    return __uint_as_float((unsigned)s << 16);
}

// ---------------------------------------------------------------------------
// Edge dtype detection: if the edge buffer is int64 (values < 2^31), every
// odd 32-bit word of the first 256 words is zero. flag=1 -> int64, 0 -> int32.
// ---------------------------------------------------------------------------
__global__ __launch_bounds__(256) void k_detect(const unsigned* __restrict__ w,
                                                int* __restrict__ flag) {
    __shared__ int anynz;
    if (threadIdx.x == 0) anynz = 0;
    __syncthreads();
    if ((threadIdx.x & 1) && w[threadIdx.x] != 0) anynz = 1;
    __syncthreads();
    if (threadIdx.x == 0) *flag = (anynz == 0) ? 1 : 0;
}

__device__ __forceinline__ int load_idx(const void* eb, int is64, long long pos) {
    if (is64) return (int)((const long long*)eb)[pos];
    return ((const int*)eb)[pos];
}

// ---------------------------------------------------------------------------
// Pass 1a: bucket totals. Bucket = dst >> 8 (256 consecutive nodes each).
// LDS histogram per block, then one atomicAdd per (block,bucket).
// ---------------------------------------------------------------------------
__global__ __launch_bounds__(256) void k_bcount(const void* __restrict__ eb,
                                                const int* __restrict__ flag,
                                                int* __restrict__ btot, int E) {
    __shared__ int hist[256];
    int t = threadIdx.x;
    hist[t] = 0;
    __syncthreads();
    int is64 = *flag;
    long long base = (long long)blockIdx.x * CHUNK;
    #pragma unroll
    for (int i = 0; i < CHUNK / 256; ++i) {
        long long e = base + t + (long long)i * 256;
        if (e < E) {
            int d = load_idx(eb, is64, (long long)E + e);
            atomicAdd(&hist[d >> 8], 1);
        }
    }
    __syncthreads();
    if (hist[t] > 0) atomicAdd(&btot[t], hist[t]);
}

// Exclusive scan of bucket totals -> bbase[0..nbuk] (bbase[nbuk]=E); init cursors.
__global__ __launch_bounds__(256) void k_scanB(const int* __restrict__ btot,
                                               int* __restrict__ bbase,
                                               int* __restrict__ gcur, int nbuk) {
    __shared__ int sh[256];
    int t = threadIdx.x;
    int v = (t < nbuk) ? btot[t] : 0;
    sh[t] = v;
    __syncthreads();
    for (int off = 1; off < 256; off <<= 1) {
        int x = (t >= off) ? sh[t - off] : 0;
        __syncthreads();
        sh[t] += x;
        __syncthreads();
    }
    int excl = sh[t] - v;
    if (t < nbuk) { bbase[t] = excl; gcur[t] = excl; }
    if (t == nbuk - 1) bbase[nbuk] = excl + v;
}

// ---------------------------------------------------------------------------
// Pass 1b: partition edges into bucket regions. One range-claim atomic per
// (block,bucket); entries packed as (src<<8)|dst_low8 (src < 2^24).
// ---------------------------------------------------------------------------
__global__ __launch_bounds__(256) void k_bfill(const void* __restrict__ eb,
                                               const int* __restrict__ flag,
                                               int* __restrict__ gcur,
                                               unsigned* __restrict__ part, int E) {
    __shared__ int hist[256];
    __shared__ int cur[256];
    int t = threadIdx.x;
    hist[t] = 0;
    __syncthreads();
    int is64 = *flag;
    long long base = (long long)blockIdx.x * CHUNK;
    int sv[CHUNK / 256];
    int dv[CHUNK / 256];
    #pragma unroll
    for (int i = 0; i < CHUNK / 256; ++i) {
        long long e = base + t + (long long)i * 256;
        if (e < E) {
            sv[i] = load_idx(eb, is64, e);
            dv[i] = load_idx(eb, is64, (long long)E + e);
            atomicAdd(&hist[dv[i] >> 8], 1);
        } else dv[i] = -1;
    }
    __syncthreads();
    if (hist[t] > 0) cur[t] = atomicAdd(&gcur[t], hist[t]);
    __syncthreads();
    #pragma unroll
    for (int i = 0; i < CHUNK / 256; ++i) {
        if (dv[i] >= 0) {
            int b = dv[i] >> 8;
            int pos = atomicAdd(&cur[b], 1);
            part[pos] = ((unsigned)sv[i] << 8) | (unsigned)(dv[i] & 255);
        }
    }
}

// ---------------------------------------------------------------------------
// Pass 2: per-bucket CSR finalize. One block per bucket (256 nodes, ~4K edges
// in an L2-hot window). LDS histogram -> scan -> rowptr/dis; LDS-cursor
// scatter of src into csr_src. No device atomics.
// ---------------------------------------------------------------------------
__global__ __launch_bounds__(256) void k_build(const unsigned* __restrict__ part,
                                               const int* __restrict__ bbase,
                                               int* __restrict__ rowptr,
                                               int* __restrict__ csr_src,
                                               float* __restrict__ dis,
                                               int N, int E) {
    __shared__ int bins[256];
    __shared__ int cur[256];
    __shared__ int sh[256];
    int t = threadIdx.x;
    int b = blockIdx.x;
    int beg = bbase[b], end = bbase[b + 1];
    bins[t] = 0;
    __syncthreads();
    for (int i = beg + t; i < end; i += 256)
        atomicAdd(&bins[part[i] & 255u], 1);
    __syncthreads();
    int v = bins[t];
    sh[t] = v;
    __syncthreads();
    for (int off = 1; off < 256; off <<= 1) {
        int x = (t >= off) ? sh[t - off] : 0;
        __syncthreads();
        sh[t] += x;
        __syncthreads();
    }
    int excl = sh[t] - v;
    int node = b * 256 + t;
    if (node < N) {
        rowptr[node] = beg + excl;
        dis[node] = rsqrtf((float)(v + 1));
    }
    cur[t] = beg + excl;
    __syncthreads();
    for (int i = beg + t; i < end; i += 256) {
        unsigned p = part[i];
        int pos = atomicAdd(&cur[p & 255u], 1);
        csr_src[pos] = (int)(p >> 8);
    }
    if (b == 0 && t == 0) rowptr[N] = E;
}

// ---------------------------------------------------------------------------
// GEMM: Hs[N,96] = bf16( dis[row] * (X[N,96] @ W[96,96]) ), f32 VALU compute.
// ---------------------------------------------------------------------------
__global__ __launch_bounds__(256) void k_gemm96(const float* __restrict__ X,
                                                const float* __restrict__ W,
                                                const float* __restrict__ dis,
                                                ushort_t* __restrict__ Hs, int N) {
    __shared__ float ws[96][96];  // 36864 B
    __shared__ float xs[64][96];  // 24576 B
    int t = threadIdx.x;

    const float4* W4 = (const float4*)W;
    float4* ws4 = (float4*)&ws[0][0];
    #pragma unroll
    for (int k = 0; k < 9; ++k) ws4[t + k * 256] = W4[t + k * 256];

    int row0 = blockIdx.x * 64;
    const float4* X4 = (const float4*)X;
    float4* xs4 = (float4*)&xs[0][0];
    #pragma unroll
    for (int k = 0; k < 6; ++k) {
        int idx = t + k * 256;      // < 1536 = 64*24
        int r = idx / 24;
        int gr = row0 + r;
        float4 v = make_float4(0.f, 0.f, 0.f, 0.f);
        if (gr < N) v = X4[(size_t)gr * 24 + (idx % 24)];
        xs4[idx] = v;
    }
    __syncthreads();

    int c = t & 31;
    int r0 = (t >> 5) * 8;
    float acc[8][3];
    #pragma unroll
    for (int r = 0; r < 8; ++r) { acc[r][0] = 0.f; acc[r][1] = 0.f; acc[r][2] = 0.f; }

    for (int k = 0; k < 96; ++k) {
        float w0 = ws[k][c], w1 = ws[k][c + 32], w2 = ws[k][c + 64];
        #pragma unroll
        for (int r = 0; r < 8; ++r) {
            float xv = xs[r0 + r][k];
            acc[r][0] = fmaf(xv, w0, acc[r][0]);
            acc[r][1] = fmaf(xv, w1, acc[r][1]);
            acc[r][2] = fmaf(xv, w2, acc[r][2]);
        }
    }
    #pragma unroll
    for (int r = 0; r < 8; ++r) {
        int gr = row0 + r0 + r;
        if (gr < N) {
            float dr = dis[gr];
            ushort_t* o = Hs + (size_t)gr * D;
            o[c]      = f2bf(dr * acc[r][0]);
            o[c + 32] = f2bf(dr * acc[r][1]);
            o[c + 64] = f2bf(dr * acc[r][2]);
        }
    }
}

// ---------------------------------------------------------------------------
// Fused aggregate + bias + tanh + LayerNorm + affine.
// a = dis[node] * ( hs[node] + sum_{src} hs[src] ); hs is bf16.
// One 32-lane group per node; lane owns features {l, l+32, l+64}.
// ---------------------------------------------------------------------------
__global__ __launch_bounds__(256) void k_agg_ln(const ushort_t* __restrict__ hs,
                                                const int* __restrict__ rowptr,
                                                const int* __restrict__ csr_src,
                                                const float* __restrict__ dis,
                                                const float* __restrict__ b,
                                                const float* __restrict__ g,
                                                const float* __restrict__ be,
                                                float* __restrict__ out, int N) {
    int node = blockIdx.x * 8 + (threadIdx.x >> 5);
    int lane = threadIdx.x & 31;
    if (node >= N) return;

    const ushort_t* hp0 = hs + (size_t)node * D;
    float a0 = bf2f(hp0[lane]);
    float a1 = bf2f(hp0[lane + 32]);
    float a2 = bf2f(hp0[lane + 64]);

    int beg = rowptr[node], end = rowptr[node + 1];
    for (int base = beg; base < end; base += 32) {
        int e = base + lane;
        int s = (e < end) ? csr_src[e] : 0;
        int cnt = end - base;
        if (cnt >= 32) {
            #pragma unroll
            for (int j = 0; j < 32; ++j) {
                int ss = __shfl(s, j, 32);
                const ushort_t* hp = hs + (size_t)ss * D;
                a0 += bf2f(hp[lane]);
                a1 += bf2f(hp[lane + 32]);
                a2 += bf2f(hp[lane + 64]);
            }
        } else {
            for (int j = 0; j < cnt; ++j) {
                int ss = __shfl(s, j, 32);
                const ushort_t* hp = hs + (size_t)ss * D;
                a0 += bf2f(hp[lane]);
                a1 += bf2f(hp[lane + 32]);
                a2 += bf2f(hp[lane + 64]);
            }
        }
    }

    float dn = dis[node];
    a0 = tanhf(fmaf(dn, a0, b[lane]));
    a1 = tanhf(fmaf(dn, a1, b[lane + 32]));
    a2 = tanhf(fmaf(dn, a2, b[lane + 64]));

    float s1 = a0 + a1 + a2;
    float s2 = a0 * a0 + a1 * a1 + a2 * a2;
    #pragma unroll
    for (int off = 16; off >= 1; off >>= 1) {
        s1 += __shfl_xor(s1, off, 32);
        s2 += __shfl_xor(s2, off, 32);
    }
    float mu = s1 * (1.f / 96.f);
    float var = s2 * (1.f / 96.f) - mu * mu;
    float inv = rsqrtf(var + LN_EPS);

    float* o = out + (size_t)node * D;
    o[lane]      = (a0 - mu) * inv * g[lane]      + be[lane];
    o[lane + 32] = (a1 - mu) * inv * g[lane + 32] + be[lane + 32];
    o[lane + 64] = (a2 - mu) * inv * g[lane + 64] + be[lane + 64];
}

// ---------------------------------------------------------------------------
extern "C" void kernel_launch(void* const* d_in, const int* in_sizes, int n_in,
                              void* d_out, int out_size, void* d_ws, size_t ws_size,
                              hipStream_t stream) {
    const float* x  = (const float*)d_in[0];
    const void*  eb = d_in[1];
    const float* W0 = (const float*)d_in[2];
    const float* b0 = (const float*)d_in[3];
    const float* g0 = (const float*)d_in[4];
    const float* be0 = (const float*)d_in[5];
    const float* W1 = (const float*)d_in[6];
    const float* b1 = (const float*)d_in[7];
    const float* g1 = (const float*)d_in[8];
    const float* be1 = (const float*)d_in[9];

    const int N = in_sizes[0] / D;
    const int E = in_sizes[1] / 2;
    const int NBUK = (N + 255) >> 8;            // 196 for N=50000
    const int NBLK = (E + CHUNK - 1) / CHUNK;   // 196 for E=800000

    auto al = [](size_t v) { return (v + 255) & ~(size_t)255; };
    char* w = (char*)d_ws;
    size_t off = 0;
    int* flag = (int*)(w + off);         off = al(off + 4);
    int* btot = (int*)(w + off);         off = al(off + 256 * 4);
    int* bbase = (int*)(w + off);        off = al(off + 257 * 4);
    int* gcur = (int*)(w + off);         off = al(off + 256 * 4);
    int* rowptr = (int*)(w + off);       off = al(off + (size_t)(N + 1) * 4);
    float* dis = (float*)(w + off);      off = al(off + (size_t)N * 4);
    int* csr_src = (int*)(w + off);      off = al(off + (size_t)E * 4);
    unsigned* part = (unsigned*)(w + off); off = al(off + (size_t)E * 4);
    ushort_t* hs = (ushort_t*)(w + off); off = al(off + (size_t)N * D * 2);
    float* outf = (float*)d_out;

    const int nbG = (N + 63) / 64;
    const int nbA = (N + 7) / 8;

    k_detect<<<1, 256, 0, stream>>>((const unsigned*)eb, flag);
    hipMemsetAsync(btot, 0, 256 * 4, stream);
    k_bcount<<<NBLK, 256, 0, stream>>>(eb, flag, btot, E);
    k_scanB<<<1, 256, 0, stream>>>(btot, bbase, gcur, NBUK);
    k_bfill<<<NBLK, 256, 0, stream>>>(eb, flag, gcur, part, E);
    k_build<<<NBUK, 256, 0, stream>>>(part, bbase, rowptr, csr_src, dis, N, E);

    // Layer 1: GEMM (dis-scaled, bf16) -> hs ; aggregate+tanh+LN -> d_out
    k_gemm96<<<nbG, 256, 0, stream>>>(x, W0, dis, hs, N);
    k_agg_ln<<<nbA, 256, 0, stream>>>(hs, rowptr, csr_src, dis, b0, g0, be0, outf, N);
    // Layer 2: GEMM (reads d_out) -> hs ; aggregate -> d_out (final)
    k_gemm96<<<nbG, 256, 0, stream>>>(outf, W1, dis, hs, N);
    k_agg_ln<<<nbA, 256, 0, stream>>>(hs, rowptr, csr_src, dis, b1, g1, be1, outf, N);
}

// Round 4
// 166.038 us; speedup vs baseline: 1.5262x; 1.1658x over previous
//
#include <hip/hip_runtime.h>
#include <hip/hip_bf16.h>

#define D 96
#define LN_EPS 1e-5f
#define CHUNK 4096   // edges per partition block

typedef unsigned short ushort_t;

__device__ __forceinline__ ushort_t f2bf(float f) {
    unsigned u = __float_as_uint(f);
    u += 0x7FFF + ((u >> 16) & 1);          // round-to-nearest-even
    return (ushort_t)(u >> 16);
}
__device__ __forceinline__ float blo(unsigned v) {   // low bf16 -> f32
    return __uint_as_float(v << 16);
}
__device__ __forceinline__ float bhi(unsigned v) {   // high bf16 -> f32
    return __uint_as_float(v & 0xffff0000u);
}

// ---------------------------------------------------------------------------
// Init: edge dtype detect + zero btot + zero sentinel row N of hs.
// ---------------------------------------------------------------------------
__global__ __launch_bounds__(256) void k_init(const unsigned* __restrict__ w,
                                              int* __restrict__ flag,
                                              int* __restrict__ btot,
                                              ushort_t* __restrict__ hs, int N) {
    __shared__ int anynz;
    int t = threadIdx.x;
    if (t == 0) anynz = 0;
    __syncthreads();
    if ((t & 1) && w[t] != 0) anynz = 1;
    btot[t] = 0;
    if (t < 48) ((unsigned*)hs)[(size_t)N * 48 + t] = 0;  // sentinel row
    __syncthreads();
    if (t == 0) *flag = (anynz == 0) ? 1 : 0;
}

__device__ __forceinline__ int load_idx(const void* eb, int is64, long long pos) {
    if (is64) return (int)((const long long*)eb)[pos];
    return ((const int*)eb)[pos];
}

// ---------------------------------------------------------------------------
// Pass 1a: bucket totals (bucket = dst >> 8).
// ---------------------------------------------------------------------------
__global__ __launch_bounds__(256) void k_bcount(const void* __restrict__ eb,
                                                const int* __restrict__ flag,
                                                int* __restrict__ btot, int E) {
    __shared__ int hist[256];
    int t = threadIdx.x;
    hist[t] = 0;
    __syncthreads();
    int is64 = *flag;
    long long base = (long long)blockIdx.x * CHUNK;
    #pragma unroll
    for (int i = 0; i < CHUNK / 256; ++i) {
        long long e = base + t + (long long)i * 256;
        if (e < E) {
            int d = load_idx(eb, is64, (long long)E + e);
            atomicAdd(&hist[d >> 8], 1);
        }
    }
    __syncthreads();
    if (hist[t] > 0) atomicAdd(&btot[t], hist[t]);
}

// Exclusive scan of bucket totals; init cursors.
__global__ __launch_bounds__(256) void k_scanB(const int* __restrict__ btot,
                                               int* __restrict__ bbase,
                                               int* __restrict__ gcur, int nbuk) {
    __shared__ int sh[256];
    int t = threadIdx.x;
    int v = (t < nbuk) ? btot[t] : 0;
    sh[t] = v;
    __syncthreads();
    for (int off = 1; off < 256; off <<= 1) {
        int x = (t >= off) ? sh[t - off] : 0;
        __syncthreads();
        sh[t] += x;
        __syncthreads();
    }
    int excl = sh[t] - v;
    if (t < nbuk) { bbase[t] = excl; gcur[t] = excl; }
    if (t == nbuk - 1) bbase[nbuk] = excl + v;
}

// ---------------------------------------------------------------------------
// Pass 1b: partition edges into bucket regions, packed (src<<8)|dst_low8.
// ---------------------------------------------------------------------------
__global__ __launch_bounds__(256) void k_bfill(const void* __restrict__ eb,
                                               const int* __restrict__ flag,
                                               int* __restrict__ gcur,
                                               unsigned* __restrict__ part, int E) {
    __shared__ int hist[256];
    __shared__ int cur[256];
    int t = threadIdx.x;
    hist[t] = 0;
    __syncthreads();
    int is64 = *flag;
    long long base = (long long)blockIdx.x * CHUNK;
    int sv[CHUNK / 256];
    int dv[CHUNK / 256];
    #pragma unroll
    for (int i = 0; i < CHUNK / 256; ++i) {
        long long e = base + t + (long long)i * 256;
        if (e < E) {
            sv[i] = load_idx(eb, is64, e);
            dv[i] = load_idx(eb, is64, (long long)E + e);
            atomicAdd(&hist[dv[i] >> 8], 1);
        } else dv[i] = -1;
    }
    __syncthreads();
    if (hist[t] > 0) cur[t] = atomicAdd(&gcur[t], hist[t]);
    __syncthreads();
    #pragma unroll
    for (int i = 0; i < CHUNK / 256; ++i) {
        if (dv[i] >= 0) {
            int b = dv[i] >> 8;
            int pos = atomicAdd(&cur[b], 1);
            part[pos] = ((unsigned)sv[i] << 8) | (unsigned)(dv[i] & 255);
        }
    }
}

// ---------------------------------------------------------------------------
// Pass 2: per-bucket CSR finalize with per-node padding to multiple of 4.
// Bucket b's padded region starts at bbase[b] + 768*b (slack = 3*256).
// Tail slots get sentinel src = N (zero row).
// ---------------------------------------------------------------------------
__global__ __launch_bounds__(256) void k_build(const unsigned* __restrict__ part,
                                               const int* __restrict__ bbase,
                                               int* __restrict__ rbeg,
                                               int* __restrict__ rend,
                                               int* __restrict__ csr_src,
                                               float* __restrict__ dis,
                                               int N) {
    __shared__ int bins[256];
    __shared__ int cur[256];
    __shared__ int sh[256];
    int t = threadIdx.x;
    int b = blockIdx.x;
    int beg = bbase[b], end = bbase[b + 1];
    bins[t] = 0;
    __syncthreads();
    for (int i = beg + t; i < end; i += 256)
        atomicAdd(&bins[part[i] & 255u], 1);
    __syncthreads();
    int deg = bins[t];
    int pdeg = (deg + 3) & ~3;
    sh[t] = pdeg;
    __syncthreads();
    for (int off = 1; off < 256; off <<= 1) {
        int x = (t >= off) ? sh[t - off] : 0;
        __syncthreads();
        sh[t] += x;
        __syncthreads();
    }
    int mybeg = beg + 768 * b + (sh[t] - pdeg);
    int node = b * 256 + t;
    if (node < N) {
        rbeg[node] = mybeg;
        rend[node] = mybeg + pdeg;
        dis[node] = rsqrtf((float)(deg + 1));
    }
    cur[t] = mybeg;
    __syncthreads();
    for (int i = beg + t; i < end; i += 256) {
        unsigned p = part[i];
        int pos = atomicAdd(&cur[p & 255u], 1);
        csr_src[pos] = (int)(p >> 8);
    }
    for (int k = deg; k < pdeg; ++k) csr_src[mybeg + k] = N;  // sentinels
}

// ---------------------------------------------------------------------------
// GEMM: Hs[N,96] = bf16( dis[row] * (X[N,96] @ W[96,96]) ), f32 VALU compute.
// ---------------------------------------------------------------------------
__global__ __launch_bounds__(256) void k_gemm96(const float* __restrict__ X,
                                                const float* __restrict__ W,
                                                const float* __restrict__ dis,
                                                ushort_t* __restrict__ Hs, int N) {
    __shared__ float ws[96][96];
    __shared__ float xs[64][96];
    int t = threadIdx.x;

    const float4* W4 = (const float4*)W;
    float4* ws4 = (float4*)&ws[0][0];
    #pragma unroll
    for (int k = 0; k < 9; ++k) ws4[t + k * 256] = W4[t + k * 256];

    int row0 = blockIdx.x * 64;
    const float4* X4 = (const float4*)X;
    float4* xs4 = (float4*)&xs[0][0];
    #pragma unroll
    for (int k = 0; k < 6; ++k) {
        int idx = t + k * 256;
        int r = idx / 24;
        int gr = row0 + r;
        float4 v = make_float4(0.f, 0.f, 0.f, 0.f);
        if (gr < N) v = X4[(size_t)gr * 24 + (idx % 24)];
        xs4[idx] = v;
    }
    __syncthreads();

    int c = t & 31;
    int r0 = (t >> 5) * 8;
    float acc[8][3];
    #pragma unroll
    for (int r = 0; r < 8; ++r) { acc[r][0] = 0.f; acc[r][1] = 0.f; acc[r][2] = 0.f; }

    for (int k = 0; k < 96; ++k) {
        float w0 = ws[k][c], w1 = ws[k][c + 32], w2 = ws[k][c + 64];
        #pragma unroll
        for (int r = 0; r < 8; ++r) {
            float xv = xs[r0 + r][k];
            acc[r][0] = fmaf(xv, w0, acc[r][0]);
            acc[r][1] = fmaf(xv, w1, acc[r][1]);
            acc[r][2] = fmaf(xv, w2, acc[r][2]);
        }
    }
    #pragma unroll
    for (int r = 0; r < 8; ++r) {
        int gr = row0 + r0 + r;
        if (gr < N) {
            float dr = dis[gr];
            ushort_t* o = Hs + (size_t)gr * D;
            o[c]      = f2bf(dr * acc[r][0]);
            o[c + 32] = f2bf(dr * acc[r][1]);
            o[c + 64] = f2bf(dr * acc[r][2]);
        }
    }
}

// ---------------------------------------------------------------------------
// Fused aggregate + bias + tanh + LayerNorm + affine, u32-packed gathers.
// 32-lane group per node. Lane l owns features {2l, 2l+1}; lanes 0-15 also
// own {64+2l, 65+2l}. Edge runs are padded to x4 (sentinel=zero row N), so
// the inner loop is a branch-free unroll-4 burst of 8 independent loads.
// ---------------------------------------------------------------------------
__global__ __launch_bounds__(256) void k_agg_ln(const ushort_t* __restrict__ hs,
                                                const int* __restrict__ rbeg,
                                                const int* __restrict__ rend,
                                                const int* __restrict__ csr_src,
                                                const float* __restrict__ dis,
                                                const float* __restrict__ b,
                                                const float* __restrict__ g,
                                                const float* __restrict__ be,
                                                float* __restrict__ out, int N) {
    int node = blockIdx.x * 8 + (threadIdx.x >> 5);
    int lane = threadIdx.x & 31;
    if (node >= N) return;

    const unsigned* h32 = (const unsigned*)hs;
    float a0, a1, a2 = 0.f, a3 = 0.f;
    {
        unsigned v = h32[(size_t)node * 48 + lane];
        a0 = blo(v); a1 = bhi(v);
        if (lane < 16) {
            unsigned u = h32[(size_t)node * 48 + 32 + lane];
            a2 = blo(u); a3 = bhi(u);
        }
    }

    int beg = rbeg[node], end = rend[node];
    for (int cb = beg; cb < end; cb += 32) {
        int m = min(32, end - cb);
        int e = cb + lane;
        int sreg = (e < end) ? csr_src[e] : 0;
        for (int j = 0; j < m; j += 4) {
            int s0 = __shfl(sreg, j, 32);
            int s1 = __shfl(sreg, j + 1, 32);
            int s2 = __shfl(sreg, j + 2, 32);
            int s3 = __shfl(sreg, j + 3, 32);
            unsigned v0 = h32[s0 * 48 + lane];
            unsigned v1 = h32[s1 * 48 + lane];
            unsigned v2 = h32[s2 * 48 + lane];
            unsigned v3 = h32[s3 * 48 + lane];
            a0 += blo(v0) + blo(v1) + blo(v2) + blo(v3);
            a1 += bhi(v0) + bhi(v1) + bhi(v2) + bhi(v3);
            if (lane < 16) {
                unsigned w0 = h32[s0 * 48 + 32 + lane];
                unsigned w1 = h32[s1 * 48 + 32 + lane];
                unsigned w2 = h32[s2 * 48 + 32 + lane];
                unsigned w3 = h32[s3 * 48 + 32 + lane];
                a2 += blo(w0) + blo(w1) + blo(w2) + blo(w3);
                a3 += bhi(w0) + bhi(w1) + bhi(w2) + bhi(w3);
            }
        }
    }

    float dn = dis[node];
    float2 b01 = ((const float2*)b)[lane];
    a0 = tanhf(fmaf(dn, a0, b01.x));
    a1 = tanhf(fmaf(dn, a1, b01.y));
    float s1 = a0 + a1;
    float s2 = a0 * a0 + a1 * a1;
    if (lane < 16) {
        float2 b23 = ((const float2*)b)[32 + lane];
        a2 = tanhf(fmaf(dn, a2, b23.x));
        a3 = tanhf(fmaf(dn, a3, b23.y));
        s1 += a2 + a3;
        s2 += a2 * a2 + a3 * a3;
    }
    #pragma unroll
    for (int off = 16; off >= 1; off >>= 1) {
        s1 += __shfl_xor(s1, off, 32);
        s2 += __shfl_xor(s2, off, 32);
    }
    float mu = s1 * (1.f / 96.f);
    float var = s2 * (1.f / 96.f) - mu * mu;
    float inv = rsqrtf(var + LN_EPS);

    float2* o2 = (float2*)(out + (size_t)node * D);
    float2 g01 = ((const float2*)g)[lane];
    float2 e01 = ((const float2*)be)[lane];
    o2[lane] = make_float2((a0 - mu) * inv * g01.x + e01.x,
                           (a1 - mu) * inv * g01.y + e01.y);
    if (lane < 16) {
        float2 g23 = ((const float2*)g)[32 + lane];
        float2 e23 = ((const float2*)be)[32 + lane];
        o2[32 + lane] = make_float2((a2 - mu) * inv * g23.x + e23.x,
                                    (a3 - mu) * inv * g23.y + e23.y);
    }
}

// ---------------------------------------------------------------------------
extern "C" void kernel_launch(void* const* d_in, const int* in_sizes, int n_in,
                              void* d_out, int out_size, void* d_ws, size_t ws_size,
                              hipStream_t stream) {
    const float* x  = (const float*)d_in[0];
    const void*  eb = d_in[1];
    const float* W0 = (const float*)d_in[2];
    const float* b0 = (const float*)d_in[3];
    const float* g0 = (const float*)d_in[4];
    const float* be0 = (const float*)d_in[5];
    const float* W1 = (const float*)d_in[6];
    const float* b1 = (const float*)d_in[7];
    const float* g1 = (const float*)d_in[8];
    const float* be1 = (const float*)d_in[9];

    const int N = in_sizes[0] / D;
    const int E = in_sizes[1] / 2;
    const int NBUK = (N + 255) >> 8;
    const int NBLK = (E + CHUNK - 1) / CHUNK;

    auto al = [](size_t v) { return (v + 255) & ~(size_t)255; };
    char* w = (char*)d_ws;
    size_t off = 0;
    int* flag = (int*)(w + off);          off = al(off + 4);
    int* btot = (int*)(w + off);          off = al(off + 256 * 4);
    int* bbase = (int*)(w + off);         off = al(off + 257 * 4);
    int* gcur = (int*)(w + off);          off = al(off + 256 * 4);
    int* rbeg = (int*)(w + off);          off = al(off + (size_t)N * 4);
    int* rend = (int*)(w + off);          off = al(off + (size_t)N * 4);
    float* dis = (float*)(w + off);       off = al(off + (size_t)N * 4);
    int* csr_src = (int*)(w + off);       off = al(off + ((size_t)E + 768 * 256) * 4);
    unsigned* part = (unsigned*)(w + off); off = al(off + (size_t)E * 4);
    ushort_t* hs = (ushort_t*)(w + off);  off = al(off + ((size_t)N + 1) * D * 2);
    float* outf = (float*)d_out;

    const int nbG = (N + 63) / 64;
    const int nbA = (N + 7) / 8;

    k_init<<<1, 256, 0, stream>>>((const unsigned*)eb, flag, btot, hs, N);
    k_bcount<<<NBLK, 256, 0, stream>>>(eb, flag, btot, E);
    k_scanB<<<1, 256, 0, stream>>>(btot, bbase, gcur, NBUK);
    k_bfill<<<NBLK, 256, 0, stream>>>(eb, flag, gcur, part, E);
    k_build<<<NBUK, 256, 0, stream>>>(part, bbase, rbeg, rend, csr_src, dis, N);

    // Layer 1
    k_gemm96<<<nbG, 256, 0, stream>>>(x, W0, dis, hs, N);
    k_agg_ln<<<nbA, 256, 0, stream>>>(hs, rbeg, rend, csr_src, dis, b0, g0, be0, outf, N);
    // Layer 2
    k_gemm96<<<nbG, 256, 0, stream>>>(outf, W1, dis, hs, N);
    k_agg_ln<<<nbA, 256, 0, stream>>>(hs, rbeg, rend, csr_src, dis, b1, g1, be1, outf, N);
}

// Round 5
// 150.527 us; speedup vs baseline: 1.6834x; 1.1030x over previous
//
#include <hip/hip_runtime.h>
#include <hip/hip_bf16.h>

#define D 96
#define LN_EPS 1e-5f
#define CHUNK 1024   // edges per partition block

typedef unsigned short ushort_t;
typedef __attribute__((ext_vector_type(8))) short short8;
typedef __attribute__((ext_vector_type(4))) float f32x4;

__device__ __forceinline__ ushort_t f2bf(float f) {
    unsigned u = __float_as_uint(f);
    u += 0x7FFF + ((u >> 16) & 1);          // round-to-nearest-even
    return (ushort_t)(u >> 16);
}
__device__ __forceinline__ float blo(unsigned v) {   // low bf16 -> f32
    return __uint_as_float(v << 16);
}
__device__ __forceinline__ float bhi(unsigned v) {   // high bf16 -> f32
    return __uint_as_float(v & 0xffff0000u);
}

// ---------------------------------------------------------------------------
// Init: edge dtype detect + zero btot + zero sentinel row N of hs.
// ---------------------------------------------------------------------------
__global__ __launch_bounds__(256) void k_init(const unsigned* __restrict__ w,
                                              int* __restrict__ flag,
                                              int* __restrict__ btot,
                                              ushort_t* __restrict__ hs, int N) {
    __shared__ int anynz;
    int t = threadIdx.x;
    if (t == 0) anynz = 0;
    __syncthreads();
    if ((t & 1) && w[t] != 0) anynz = 1;
    btot[t] = 0;
    if (t < 48) ((unsigned*)hs)[(size_t)N * 48 + t] = 0;  // sentinel row
    __syncthreads();
    if (t == 0) *flag = (anynz == 0) ? 1 : 0;
}

__device__ __forceinline__ int load_idx(const void* eb, int is64, long long pos) {
    if (is64) return (int)((const long long*)eb)[pos];
    return ((const int*)eb)[pos];
}

// x (f32) -> xb (bf16), grid-stride over float4s.
__global__ __launch_bounds__(256) void k_convx(const float* __restrict__ x,
                                               ushort_t* __restrict__ xb, int n4) {
    int stride = gridDim.x * 256;
    for (int i = blockIdx.x * 256 + threadIdx.x; i < n4; i += stride) {
        float4 v = ((const float4*)x)[i];
        ushort4 o;
        o.x = f2bf(v.x); o.y = f2bf(v.y); o.z = f2bf(v.z); o.w = f2bf(v.w);
        ((ushort4*)xb)[i] = o;
    }
}

// W0,W1 (f32 [k][c]) -> Wt0,Wt1 (bf16 transposed [c][k]).
__global__ __launch_bounds__(256) void k_convW(const float* __restrict__ W0,
                                               const float* __restrict__ W1,
                                               ushort_t* __restrict__ Wt0,
                                               ushort_t* __restrict__ Wt1) {
    int idx = blockIdx.x * 256 + threadIdx.x;
    if (idx >= 2 * 96 * 96) return;
    int sel = idx / 9216, i = idx % 9216;
    int c = i / 96, k = i % 96;
    const float* W = sel ? W1 : W0;
    ushort_t* Wt = sel ? Wt1 : Wt0;
    Wt[c * 96 + k] = f2bf(W[k * 96 + c]);
}

// ---------------------------------------------------------------------------
// Pass 1a: bucket totals (bucket = dst >> 8).
// ---------------------------------------------------------------------------
__global__ __launch_bounds__(256) void k_bcount(const void* __restrict__ eb,
                                                const int* __restrict__ flag,
                                                int* __restrict__ btot, int E) {
    __shared__ int hist[256];
    int t = threadIdx.x;
    hist[t] = 0;
    __syncthreads();
    int is64 = *flag;
    long long base = (long long)blockIdx.x * CHUNK;
    #pragma unroll
    for (int i = 0; i < CHUNK / 256; ++i) {
        long long e = base + t + (long long)i * 256;
        if (e < E) {
            int d = load_idx(eb, is64, (long long)E + e);
            atomicAdd(&hist[d >> 8], 1);
        }
    }
    __syncthreads();
    if (hist[t] > 0) atomicAdd(&btot[t], hist[t]);
}

// Exclusive scan of bucket totals; init cursors.
__global__ __launch_bounds__(256) void k_scanB(const int* __restrict__ btot,
                                               int* __restrict__ bbase,
                                               int* __restrict__ gcur, int nbuk) {
    __shared__ int sh[256];
    int t = threadIdx.x;
    int v = (t < nbuk) ? btot[t] : 0;
    sh[t] = v;
    __syncthreads();
    for (int off = 1; off < 256; off <<= 1) {
        int x = (t >= off) ? sh[t - off] : 0;
        __syncthreads();
        sh[t] += x;
        __syncthreads();
    }
    int excl = sh[t] - v;
    if (t < nbuk) { bbase[t] = excl; gcur[t] = excl; }
    if (t == nbuk - 1) bbase[nbuk] = excl + v;
}

// ---------------------------------------------------------------------------
// Pass 1b: partition edges into bucket regions, packed (src<<8)|dst_low8.
// ---------------------------------------------------------------------------
__global__ __launch_bounds__(256) void k_bfill(const void* __restrict__ eb,
                                               const int* __restrict__ flag,
                                               int* __restrict__ gcur,
                                               unsigned* __restrict__ part, int E) {
    __shared__ int hist[256];
    __shared__ int cur[256];
    int t = threadIdx.x;
    hist[t] = 0;
    __syncthreads();
    int is64 = *flag;
    long long base = (long long)blockIdx.x * CHUNK;
    int sv[CHUNK / 256];
    int dv[CHUNK / 256];
    #pragma unroll
    for (int i = 0; i < CHUNK / 256; ++i) {
        long long e = base + t + (long long)i * 256;
        if (e < E) {
            sv[i] = load_idx(eb, is64, e);
            dv[i] = load_idx(eb, is64, (long long)E + e);
            atomicAdd(&hist[dv[i] >> 8], 1);
        } else dv[i] = -1;
    }
    __syncthreads();
    if (hist[t] > 0) cur[t] = atomicAdd(&gcur[t], hist[t]);
    __syncthreads();
    #pragma unroll
    for (int i = 0; i < CHUNK / 256; ++i) {
        if (dv[i] >= 0) {
            int b = dv[i] >> 8;
            int pos = atomicAdd(&cur[b], 1);
            part[pos] = ((unsigned)sv[i] << 8) | (unsigned)(dv[i] & 255);
        }
    }
}

// ---------------------------------------------------------------------------
// Pass 2: per-bucket CSR finalize with per-node padding to multiple of 4.
// Bucket b's padded region starts at bbase[b] + 768*b (slack = 3*256).
// Tail slots get sentinel src = N (zero row).
// ---------------------------------------------------------------------------
__global__ __launch_bounds__(256) void k_build(const unsigned* __restrict__ part,
                                               const int* __restrict__ bbase,
                                               int* __restrict__ rbeg,
                                               int* __restrict__ rend,
                                               int* __restrict__ csr_src,
                                               float* __restrict__ dis,
                                               int N) {
    __shared__ int bins[256];
    __shared__ int cur[256];
    __shared__ int sh[256];
    int t = threadIdx.x;
    int b = blockIdx.x;
    int beg = bbase[b], end = bbase[b + 1];
    bins[t] = 0;
    __syncthreads();
    for (int i = beg + t; i < end; i += 256)
        atomicAdd(&bins[part[i] & 255u], 1);
    __syncthreads();
    int deg = bins[t];
    int pdeg = (deg + 3) & ~3;
    sh[t] = pdeg;
    __syncthreads();
    for (int off = 1; off < 256; off <<= 1) {
        int x = (t >= off) ? sh[t - off] : 0;
        __syncthreads();
        sh[t] += x;
        __syncthreads();
    }
    int mybeg = beg + 768 * b + (sh[t] - pdeg);
    int node = b * 256 + t;
    if (node < N) {
        rbeg[node] = mybeg;
        rend[node] = mybeg + pdeg;
        dis[node] = rsqrtf((float)(deg + 1));
    }
    cur[t] = mybeg;
    __syncthreads();
    for (int i = beg + t; i < end; i += 256) {
        unsigned p = part[i];
        int pos = atomicAdd(&cur[p & 255u], 1);
        csr_src[pos] = (int)(p >> 8);
    }
    for (int k = deg; k < pdeg; ++k) csr_src[mybeg + k] = N;  // sentinels
}

// ---------------------------------------------------------------------------
// MFMA GEMM: Hs[N,96] = bf16( dis[row] * (A[N,96] @ W[96,96]) ).
// A is bf16 row-major; Wt is bf16 TRANSPOSED ([c][k]) so B-frags are
// contiguous. 64 rows/block, 4 waves, each wave one 16-row tile.
// mfma_f32_16x16x32_bf16: A[row=l&15][k=(l>>4)*8+j], B[k][col=l&15],
// D[row=(l>>4)*4+reg][col=l&15] (m89-verified C/D layout).
// LDS rows padded to 104 (208B = 52 banks -> 2-way conflicts, free).
// ---------------------------------------------------------------------------
__global__ __launch_bounds__(256) void k_gemm_mfma(const ushort_t* __restrict__ A,
                                                   const ushort_t* __restrict__ Wt,
                                                   const float* __restrict__ dis,
                                                   ushort_t* __restrict__ Hs, int N) {
    __shared__ ushort_t As[64][104];
    __shared__ ushort_t Bs[96][104];
    int t = threadIdx.x;
    int row0 = blockIdx.x * 64;

    #pragma unroll
    for (int i = 0; i < 3; ++i) {                 // stage A: 64x96 = 768 chunks
        int idx = t + i * 256;
        int r = idx / 12, c8 = idx % 12;
        short8 v = {0, 0, 0, 0, 0, 0, 0, 0};
        if (row0 + r < N) v = *(const short8*)(A + (size_t)(row0 + r) * 96 + c8 * 8);
        *(short8*)&As[r][c8 * 8] = v;
    }
    #pragma unroll
    for (int i = 0; i < 5; ++i) {                 // stage Wt: 96x96 = 1152 chunks
        int idx = t + i * 256;
        if (idx < 1152) {
            int r = idx / 12, c8 = idx % 12;
            *(short8*)&Bs[r][c8 * 8] = *(const short8*)(Wt + r * 96 + c8 * 8);
        }
    }
    __syncthreads();

    int w = t >> 6, l = t & 63;
    int lr = l & 15, lq = l >> 4;
    f32x4 acc[6];
    #pragma unroll
    for (int c = 0; c < 6; ++c) acc[c] = (f32x4){0.f, 0.f, 0.f, 0.f};

    #pragma unroll
    for (int q = 0; q < 3; ++q) {
        short8 af = *(const short8*)&As[w * 16 + lr][q * 32 + lq * 8];
        #pragma unroll
        for (int c = 0; c < 6; ++c) {
            short8 bf = *(const short8*)&Bs[c * 16 + lr][q * 32 + lq * 8];
            acc[c] = __builtin_amdgcn_mfma_f32_16x16x32_bf16(af, bf, acc[c], 0, 0, 0);
        }
    }

    int rbase = row0 + w * 16 + lq * 4;
    #pragma unroll
    for (int r = 0; r < 4; ++r) {
        int gr = rbase + r;
        if (gr < N) {
            float dr = dis[gr];
            ushort_t* o = Hs + (size_t)gr * 96 + lr;
            #pragma unroll
            for (int c = 0; c < 6; ++c) o[c * 16] = f2bf(dr * acc[c][r]);
        }
    }
}

// ---------------------------------------------------------------------------
// Fused aggregate + bias + tanh + LayerNorm + affine, u32-packed gathers.
// 32-lane group per node; lane l owns features {2l,2l+1}, lanes 0-15 also
// {64+2l,65+2l}. Edge runs padded to x4 with sentinel row N (zeros).
// BF16OUT: write bf16 (layer-1 intermediate) else f32 (final output).
// ---------------------------------------------------------------------------
template<bool BF16OUT>
__global__ __launch_bounds__(256) void k_agg_ln(const ushort_t* __restrict__ hs,
                                                const int* __restrict__ rbeg,
                                                const int* __restrict__ rend,
                                                const int* __restrict__ csr_src,
                                                const float* __restrict__ dis,
                                                const float* __restrict__ b,
                                                const float* __restrict__ g,
                                                const float* __restrict__ be,
                                                void* __restrict__ outp, int N) {
    int node = blockIdx.x * 8 + (threadIdx.x >> 5);
    int lane = threadIdx.x & 31;
    if (node >= N) return;

    const unsigned* h32 = (const unsigned*)hs;
    float a0, a1, a2 = 0.f, a3 = 0.f;
    {
        unsigned v = h32[(size_t)node * 48 + lane];
        a0 = blo(v); a1 = bhi(v);
        if (lane < 16) {
            unsigned u = h32[(size_t)node * 48 + 32 + lane];
            a2 = blo(u); a3 = bhi(u);
        }
    }

    int beg = rbeg[node], end = rend[node];
    for (int cb = beg; cb < end; cb += 32) {
        int m = min(32, end - cb);
        int e = cb + lane;
        int sreg = (e < end) ? csr_src[e] : 0;
        for (int j = 0; j < m; j += 4) {
            int s0 = __shfl(sreg, j, 32);
            int s1 = __shfl(sreg, j + 1, 32);
            int s2 = __shfl(sreg, j + 2, 32);
            int s3 = __shfl(sreg, j + 3, 32);
            unsigned v0 = h32[s0 * 48 + lane];
            unsigned v1 = h32[s1 * 48 + lane];
            unsigned v2 = h32[s2 * 48 + lane];
            unsigned v3 = h32[s3 * 48 + lane];
            a0 += blo(v0) + blo(v1) + blo(v2) + blo(v3);
            a1 += bhi(v0) + bhi(v1) + bhi(v2) + bhi(v3);
            if (lane < 16) {
                unsigned w0 = h32[s0 * 48 + 32 + lane];
                unsigned w1 = h32[s1 * 48 + 32 + lane];
                unsigned w2 = h32[s2 * 48 + 32 + lane];
                unsigned w3 = h32[s3 * 48 + 32 + lane];
                a2 += blo(w0) + blo(w1) + blo(w2) + blo(w3);
                a3 += bhi(w0) + bhi(w1) + bhi(w2) + bhi(w3);
            }
        }
    }

    float dn = dis[node];
    float2 b01 = ((const float2*)b)[lane];
    a0 = tanhf(fmaf(dn, a0, b01.x));
    a1 = tanhf(fmaf(dn, a1, b01.y));
    float s1 = a0 + a1;
    float s2 = a0 * a0 + a1 * a1;
    if (lane < 16) {
        float2 b23 = ((const float2*)b)[32 + lane];
        a2 = tanhf(fmaf(dn, a2, b23.x));
        a3 = tanhf(fmaf(dn, a3, b23.y));
        s1 += a2 + a3;
        s2 += a2 * a2 + a3 * a3;
    }
    #pragma unroll
    for (int off = 16; off >= 1; off >>= 1) {
        s1 += __shfl_xor(s1, off, 32);
        s2 += __shfl_xor(s2, off, 32);
    }
    float mu = s1 * (1.f / 96.f);
    float var = s2 * (1.f / 96.f) - mu * mu;
    float inv = rsqrtf(var + LN_EPS);

    float2 g01 = ((const float2*)g)[lane];
    float2 e01 = ((const float2*)be)[lane];
    float r0 = (a0 - mu) * inv * g01.x + e01.x;
    float r1 = (a1 - mu) * inv * g01.y + e01.y;
    if (BF16OUT) {
        unsigned* o32 = (unsigned*)outp + (size_t)node * 48;
        o32[lane] = ((unsigned)f2bf(r1) << 16) | (unsigned)f2bf(r0);
        if (lane < 16) {
            float2 g23 = ((const float2*)g)[32 + lane];
            float2 e23 = ((const float2*)be)[32 + lane];
            float r2 = (a2 - mu) * inv * g23.x + e23.x;
            float r3 = (a3 - mu) * inv * g23.y + e23.y;
            o32[32 + lane] = ((unsigned)f2bf(r3) << 16) | (unsigned)f2bf(r2);
        }
    } else {
        float2* o2 = (float2*)((float*)outp + (size_t)node * D);
        o2[lane] = make_float2(r0, r1);
        if (lane < 16) {
            float2 g23 = ((const float2*)g)[32 + lane];
            float2 e23 = ((const float2*)be)[32 + lane];
            o2[32 + lane] = make_float2((a2 - mu) * inv * g23.x + e23.x,
                                        (a3 - mu) * inv * g23.y + e23.y);
        }
    }
}

// ---------------------------------------------------------------------------
extern "C" void kernel_launch(void* const* d_in, const int* in_sizes, int n_in,
                              void* d_out, int out_size, void* d_ws, size_t ws_size,
                              hipStream_t stream) {
    const float* x  = (const float*)d_in[0];
    const void*  eb = d_in[1];
    const float* W0 = (const float*)d_in[2];
    const float* b0 = (const float*)d_in[3];
    const float* g0 = (const float*)d_in[4];
    const float* be0 = (const float*)d_in[5];
    const float* W1 = (const float*)d_in[6];
    const float* b1 = (const float*)d_in[7];
    const float* g1 = (const float*)d_in[8];
    const float* be1 = (const float*)d_in[9];

    const int N = in_sizes[0] / D;
    const int E = in_sizes[1] / 2;
    const int NBUK = (N + 255) >> 8;
    const int NBLK = (E + CHUNK - 1) / CHUNK;

    auto al = [](size_t v) { return (v + 255) & ~(size_t)255; };
    char* w = (char*)d_ws;
    size_t off = 0;
    int* flag = (int*)(w + off);          off = al(off + 4);
    int* btot = (int*)(w + off);          off = al(off + 256 * 4);
    int* bbase = (int*)(w + off);         off = al(off + 257 * 4);
    int* gcur = (int*)(w + off);          off = al(off + 256 * 4);
    int* rbeg = (int*)(w + off);          off = al(off + (size_t)N * 4);
    int* rend = (int*)(w + off);          off = al(off + (size_t)N * 4);
    float* dis = (float*)(w + off);       off = al(off + (size_t)N * 4);
    int* csr_src = (int*)(w + off);       off = al(off + ((size_t)E + 768 * 256) * 4);
    unsigned* part = (unsigned*)(w + off); off = al(off + (size_t)E * 4);
    ushort_t* hs = (ushort_t*)(w + off);  off = al(off + ((size_t)N + 1) * D * 2);
    ushort_t* xb = (ushort_t*)(w + off);  off = al(off + (size_t)N * D * 2);
    ushort_t* h1b = (ushort_t*)(w + off); off = al(off + (size_t)N * D * 2);
    ushort_t* Wt0 = (ushort_t*)(w + off); off = al(off + 9216 * 2);
    ushort_t* Wt1 = (ushort_t*)(w + off); off = al(off + 9216 * 2);
    float* outf = (float*)d_out;

    const int nbG = (N + 63) / 64;
    const int nbA = (N + 7) / 8;
    const int n4 = (N * D) / 4;

    k_init<<<1, 256, 0, stream>>>((const unsigned*)eb, flag, btot, hs, N);
    k_convx<<<2048, 256, 0, stream>>>(x, xb, n4);
    k_convW<<<72, 256, 0, stream>>>(W0, W1, Wt0, Wt1);
    k_bcount<<<NBLK, 256, 0, stream>>>(eb, flag, btot, E);
    k_scanB<<<1, 256, 0, stream>>>(btot, bbase, gcur, NBUK);
    k_bfill<<<NBLK, 256, 0, stream>>>(eb, flag, gcur, part, E);
    k_build<<<NBUK, 256, 0, stream>>>(part, bbase, rbeg, rend, csr_src, dis, N);

    // Layer 1: MFMA GEMM -> hs ; aggregate+tanh+LN -> h1b (bf16)
    k_gemm_mfma<<<nbG, 256, 0, stream>>>(xb, Wt0, dis, hs, N);
    k_agg_ln<true><<<nbA, 256, 0, stream>>>(hs, rbeg, rend, csr_src, dis,
                                            b0, g0, be0, (void*)h1b, N);
    // Layer 2: MFMA GEMM (reads h1b) -> hs ; aggregate -> d_out (f32)
    k_gemm_mfma<<<nbG, 256, 0, stream>>>(h1b, Wt1, dis, hs, N);
    k_agg_ln<false><<<nbA, 256, 0, stream>>>(hs, rbeg, rend, csr_src, dis,
                                             b1, g1, be1, (void*)outf, N);
}

// Round 6
// 122.067 us; speedup vs baseline: 2.0759x; 1.2332x over previous
//
#include <hip/hip_runtime.h>
#include <hip/hip_bf16.h>
#include <type_traits>

#define D 96
#define LN_EPS 1e-5f
#define CHUNK 1024        // edges per partition block
#define BCAP 8192         // per-bucket fixed capacity in part[] (mean 4096, 64 sigma)
#define BCAPP (BCAP + 1792) // per-bucket region in csr_src (pad-8 slack = 7*256)

typedef unsigned short ushort_t;
typedef __attribute__((ext_vector_type(8))) short short8;
typedef __attribute__((ext_vector_type(4))) float f32x4;

__device__ __forceinline__ ushort_t f2bf(float f) {
    unsigned u = __float_as_uint(f);
    u += 0x7FFF + ((u >> 16) & 1);          // round-to-nearest-even
    return (ushort_t)(u >> 16);
}
__device__ __forceinline__ float blo(unsigned v) {   // low bf16 -> f32
    return __uint_as_float(v << 16);
}
__device__ __forceinline__ float bhi(unsigned v) {   // high bf16 -> f32
    return __uint_as_float(v & 0xffff0000u);
}

// ---------------------------------------------------------------------------
// Init (block 0): edge dtype detect + gcur = b*BCAP + zero hs sentinel row.
// Blocks 1..72: W0,W1 (f32 [k][c]) -> Wt0,Wt1 (bf16 transposed [c][k]).
// ---------------------------------------------------------------------------
__global__ __launch_bounds__(256) void k_init(const unsigned* __restrict__ w,
                                              int* __restrict__ flag,
                                              int* __restrict__ gcur,
                                              ushort_t* __restrict__ hs, int N,
                                              int nbuk,
                                              const float* __restrict__ W0,
                                              const float* __restrict__ W1,
                                              ushort_t* __restrict__ Wt0,
                                              ushort_t* __restrict__ Wt1) {
    int t = threadIdx.x;
    if (blockIdx.x == 0) {
        __shared__ int anynz;
        if (t == 0) anynz = 0;
        __syncthreads();
        if ((t & 1) && w[t] != 0) anynz = 1;
        if (t < nbuk) gcur[t] = t * BCAP;
        if (t < 48) ((unsigned*)hs)[(size_t)N * 48 + t] = 0;  // sentinel row
        __syncthreads();
        if (t == 0) *flag = (anynz == 0) ? 1 : 0;
    } else {
        int idx = (blockIdx.x - 1) * 256 + t;   // < 18432
        int sel = idx / 9216, i = idx % 9216;
        int c = i / 96, k = i % 96;
        const float* W = sel ? W1 : W0;
        ushort_t* Wt = sel ? Wt1 : Wt0;
        Wt[c * 96 + k] = f2bf(W[k * 96 + c]);
    }
}

__device__ __forceinline__ int load_idx(const void* eb, int is64, long long pos) {
    if (is64) return (int)((const long long*)eb)[pos];
    return ((const int*)eb)[pos];
}

// ---------------------------------------------------------------------------
// Partition edges into fixed-capacity bucket regions (bucket = dst >> 8).
// One range-claim atomic per (block,bucket); entry = (src<<8)|dst_low8.
// ---------------------------------------------------------------------------
__global__ __launch_bounds__(256) void k_bfill(const void* __restrict__ eb,
                                               const int* __restrict__ flag,
                                               int* __restrict__ gcur,
                                               unsigned* __restrict__ part, int E) {
    __shared__ int hist[256];
    __shared__ int cur[256];
    int t = threadIdx.x;
    hist[t] = 0;
    __syncthreads();
    int is64 = *flag;
    long long base = (long long)blockIdx.x * CHUNK;
    int sv[CHUNK / 256];
    int dv[CHUNK / 256];
    #pragma unroll
    for (int i = 0; i < CHUNK / 256; ++i) {
        long long e = base + t + (long long)i * 256;
        if (e < E) {
            sv[i] = load_idx(eb, is64, e);
            dv[i] = load_idx(eb, is64, (long long)E + e);
            atomicAdd(&hist[dv[i] >> 8], 1);
        } else dv[i] = -1;
    }
    __syncthreads();
    if (hist[t] > 0) cur[t] = atomicAdd(&gcur[t], hist[t]);
    __syncthreads();
    #pragma unroll
    for (int i = 0; i < CHUNK / 256; ++i) {
        if (dv[i] >= 0) {
            int b = dv[i] >> 8;
            int pos = atomicAdd(&cur[b], 1);
            part[pos] = ((unsigned)sv[i] << 8) | (unsigned)(dv[i] & 255);
        }
    }
}

// ---------------------------------------------------------------------------
// Per-bucket CSR finalize, per-node padding to multiple of 8 (sentinel = N).
// Bucket b: part region [b*BCAP, gcur[b]); csr region starts at b*BCAPP.
// ---------------------------------------------------------------------------
__global__ __launch_bounds__(256) void k_build(const unsigned* __restrict__ part,
                                               const int* __restrict__ gcur,
                                               int* __restrict__ rbeg,
                                               int* __restrict__ rend,
                                               int* __restrict__ csr_src,
                                               float* __restrict__ dis,
                                               int N) {
    __shared__ int bins[256];
    __shared__ int cur[256];
    __shared__ int sh[256];
    int t = threadIdx.x;
    int b = blockIdx.x;
    int beg = b * BCAP, end = gcur[b];
    bins[t] = 0;
    __syncthreads();
    for (int i = beg + t; i < end; i += 256)
        atomicAdd(&bins[part[i] & 255u], 1);
    __syncthreads();
    int deg = bins[t];
    int pdeg = (deg + 7) & ~7;
    sh[t] = pdeg;
    __syncthreads();
    for (int off = 1; off < 256; off <<= 1) {
        int x = (t >= off) ? sh[t - off] : 0;
        __syncthreads();
        sh[t] += x;
        __syncthreads();
    }
    int mybeg = b * BCAPP + (sh[t] - pdeg);
    int node = b * 256 + t;
    if (node < N) {
        rbeg[node] = mybeg;
        rend[node] = mybeg + pdeg;
        dis[node] = rsqrtf((float)(deg + 1));
    }
    cur[t] = mybeg;
    __syncthreads();
    for (int i = beg + t; i < end; i += 256) {
        unsigned p = part[i];
        int pos = atomicAdd(&cur[p & 255u], 1);
        csr_src[pos] = (int)(p >> 8);
    }
    for (int k = deg; k < pdeg; ++k) csr_src[mybeg + k] = N;  // sentinels
}

// ---------------------------------------------------------------------------
// MFMA GEMM: Hs[N,96] = bf16( dis[row] * (A[N,96] @ W[96,96]) ).
// A is f32 (layer 1, converted during LDS staging) or bf16 row-major.
// Wt is bf16 TRANSPOSED ([c][k]). 64 rows/block, 4 waves, 16 rows/wave.
// mfma_f32_16x16x32_bf16: A[row=l&15][k=(l>>4)*8+j], B[k][col=l&15],
// D[row=(l>>4)*4+reg][col=l&15] (m89-verified C/D layout).
// LDS rows padded to 104 elems (208B) -> only 2-way conflicts (free).
// ---------------------------------------------------------------------------
template<typename T>
__global__ __launch_bounds__(256) void k_gemm_mfma(const T* __restrict__ A,
                                                   const ushort_t* __restrict__ Wt,
                                                   const float* __restrict__ dis,
                                                   ushort_t* __restrict__ Hs, int N) {
    __shared__ ushort_t As[64][104];
    __shared__ ushort_t Bs[96][104];
    int t = threadIdx.x;
    int row0 = blockIdx.x * 64;

    if constexpr (std::is_same<T, float>::value) {
        const float4* X4 = (const float4*)A;
        #pragma unroll
        for (int i = 0; i < 6; ++i) {             // 64x24 float4 = 1536 chunks
            int idx = t + i * 256;
            int r = idx / 24, c4 = idx % 24;
            float4 v = make_float4(0.f, 0.f, 0.f, 0.f);
            if (row0 + r < N) v = X4[(size_t)(row0 + r) * 24 + c4];
            ushort4 o;
            o.x = f2bf(v.x); o.y = f2bf(v.y); o.z = f2bf(v.z); o.w = f2bf(v.w);
            *(ushort4*)&As[r][c4 * 4] = o;
        }
    } else {
        #pragma unroll
        for (int i = 0; i < 3; ++i) {             // 64x12 short8 = 768 chunks
            int idx = t + i * 256;
            int r = idx / 12, c8 = idx % 12;
            short8 v = {0, 0, 0, 0, 0, 0, 0, 0};
            if (row0 + r < N) v = *(const short8*)(A + (size_t)(row0 + r) * 96 + c8 * 8);
            *(short8*)&As[r][c8 * 8] = v;
        }
    }
    #pragma unroll
    for (int i = 0; i < 5; ++i) {                 // 96x12 short8 = 1152 chunks
        int idx = t + i * 256;
        if (idx < 1152) {
            int r = idx / 12, c8 = idx % 12;
            *(short8*)&Bs[r][c8 * 8] = *(const short8*)(Wt + r * 96 + c8 * 8);
        }
    }
    __syncthreads();

    int w = t >> 6, l = t & 63;
    int lr = l & 15, lq = l >> 4;
    f32x4 acc[6];
    #pragma unroll
    for (int c = 0; c < 6; ++c) acc[c] = (f32x4){0.f, 0.f, 0.f, 0.f};

    #pragma unroll
    for (int q = 0; q < 3; ++q) {
        short8 af = *(const short8*)&As[w * 16 + lr][q * 32 + lq * 8];
        #pragma unroll
        for (int c = 0; c < 6; ++c) {
            short8 bf = *(const short8*)&Bs[c * 16 + lr][q * 32 + lq * 8];
            acc[c] = __builtin_amdgcn_mfma_f32_16x16x32_bf16(af, bf, acc[c], 0, 0, 0);
        }
    }

    int rbase = row0 + w * 16 + lq * 4;
    #pragma unroll
    for (int r = 0; r < 4; ++r) {
        int gr = rbase + r;
        if (gr < N) {
            float dr = dis[gr];
            ushort_t* o = Hs + (size_t)gr * 96 + lr;
            #pragma unroll
            for (int c = 0; c < 6; ++c) o[c * 16] = f2bf(dr * acc[c][r]);
        }
    }
}

// ---------------------------------------------------------------------------
// Fused aggregate + bias + tanh + LayerNorm + affine, u32-packed gathers.
// 32-lane group per node; lane l owns features {2l,2l+1}, lanes 0-15 also
// {64+2l,65+2l}. Edge runs padded to x8 with sentinel row N (zeros), so the
// inner loop is a branch-free unroll-8 burst (16/32 loads in flight/group).
// BF16OUT: write bf16 (layer-1 intermediate) else f32 (final output).
// ---------------------------------------------------------------------------
template<bool BF16OUT>
__global__ __launch_bounds__(256) void k_agg_ln(const ushort_t* __restrict__ hs,
                                                const int* __restrict__ rbeg,
                                                const int* __restrict__ rend,
                                                const int* __restrict__ csr_src,
                                                const float* __restrict__ dis,
                                                const float* __restrict__ b,
                                                const float* __restrict__ g,
                                                const float* __restrict__ be,
                                                void* __restrict__ outp, int N) {
    int node = blockIdx.x * 8 + (threadIdx.x >> 5);
    int lane = threadIdx.x & 31;
    if (node >= N) return;

    const unsigned* h32 = (const unsigned*)hs;
    float a0, a1, a2 = 0.f, a3 = 0.f;
    {
        unsigned v = h32[(size_t)node * 48 + lane];
        a0 = blo(v); a1 = bhi(v);
        if (lane < 16) {
            unsigned u = h32[(size_t)node * 48 + 32 + lane];
            a2 = blo(u); a3 = bhi(u);
        }
    }

    int beg = rbeg[node], end = rend[node];
    for (int cb = beg; cb < end; cb += 32) {
        int m = min(32, end - cb);
        int e = cb + lane;
        int sreg = (e < end) ? csr_src[e] : 0;
        for (int j = 0; j < m; j += 8) {
            int s0 = __shfl(sreg, j, 32);
            int s1 = __shfl(sreg, j + 1, 32);
            int s2 = __shfl(sreg, j + 2, 32);
            int s3 = __shfl(sreg, j + 3, 32);
            int s4 = __shfl(sreg, j + 4, 32);
            int s5 = __shfl(sreg, j + 5, 32);
            int s6 = __shfl(sreg, j + 6, 32);
            int s7 = __shfl(sreg, j + 7, 32);
            unsigned v0 = h32[s0 * 48 + lane];
            unsigned v1 = h32[s1 * 48 + lane];
            unsigned v2 = h32[s2 * 48 + lane];
            unsigned v3 = h32[s3 * 48 + lane];
            unsigned v4 = h32[s4 * 48 + lane];
            unsigned v5 = h32[s5 * 48 + lane];
            unsigned v6 = h32[s6 * 48 + lane];
            unsigned v7 = h32[s7 * 48 + lane];
            a0 += blo(v0) + blo(v1) + blo(v2) + blo(v3)
                + blo(v4) + blo(v5) + blo(v6) + blo(v7);
            a1 += bhi(v0) + bhi(v1) + bhi(v2) + bhi(v3)
                + bhi(v4) + bhi(v5) + bhi(v6) + bhi(v7);
            if (lane < 16) {
                unsigned w0 = h32[s0 * 48 + 32 + lane];
                unsigned w1 = h32[s1 * 48 + 32 + lane];
                unsigned w2 = h32[s2 * 48 + 32 + lane];
                unsigned w3 = h32[s3 * 48 + 32 + lane];
                unsigned w4 = h32[s4 * 48 + 32 + lane];
                unsigned w5 = h32[s5 * 48 + 32 + lane];
                unsigned w6 = h32[s6 * 48 + 32 + lane];
                unsigned w7 = h32[s7 * 48 + 32 + lane];
                a2 += blo(w0) + blo(w1) + blo(w2) + blo(w3)
                    + blo(w4) + blo(w5) + blo(w6) + blo(w7);
                a3 += bhi(w0) + bhi(w1) + bhi(w2) + bhi(w3)
                    + bhi(w4) + bhi(w5) + bhi(w6) + bhi(w7);
            }
        }
    }

    float dn = dis[node];
    float2 b01 = ((const float2*)b)[lane];
    a0 = tanhf(fmaf(dn, a0, b01.x));
    a1 = tanhf(fmaf(dn, a1, b01.y));
    float s1 = a0 + a1;
    float s2 = a0 * a0 + a1 * a1;
    if (lane < 16) {
        float2 b23 = ((const float2*)b)[32 + lane];
        a2 = tanhf(fmaf(dn, a2, b23.x));
        a3 = tanhf(fmaf(dn, a3, b23.y));
        s1 += a2 + a3;
        s2 += a2 * a2 + a3 * a3;
    }
    #pragma unroll
    for (int off = 16; off >= 1; off >>= 1) {
        s1 += __shfl_xor(s1, off, 32);
        s2 += __shfl_xor(s2, off, 32);
    }
    float mu = s1 * (1.f / 96.f);
    float var = s2 * (1.f / 96.f) - mu * mu;
    float inv = rsqrtf(var + LN_EPS);

    float2 g01 = ((const float2*)g)[lane];
    float2 e01 = ((const float2*)be)[lane];
    float r0 = (a0 - mu) * inv * g01.x + e01.x;
    float r1 = (a1 - mu) * inv * g01.y + e01.y;
    if (BF16OUT) {
        unsigned* o32 = (unsigned*)outp + (size_t)node * 48;
        o32[lane] = ((unsigned)f2bf(r1) << 16) | (unsigned)f2bf(r0);
        if (lane < 16) {
            float2 g23 = ((const float2*)g)[32 + lane];
            float2 e23 = ((const float2*)be)[32 + lane];
            float r2 = (a2 - mu) * inv * g23.x + e23.x;
            float r3 = (a3 - mu) * inv * g23.y + e23.y;
            o32[32 + lane] = ((unsigned)f2bf(r3) << 16) | (unsigned)f2bf(r2);
        }
    } else {
        float2* o2 = (float2*)((float*)outp + (size_t)node * D);
        o2[lane] = make_float2(r0, r1);
        if (lane < 16) {
            float2 g23 = ((const float2*)g)[32 + lane];
            float2 e23 = ((const float2*)be)[32 + lane];
            o2[32 + lane] = make_float2((a2 - mu) * inv * g23.x + e23.x,
                                        (a3 - mu) * inv * g23.y + e23.y);
        }
    }
}

// ---------------------------------------------------------------------------
extern "C" void kernel_launch(void* const* d_in, const int* in_sizes, int n_in,
                              void* d_out, int out_size, void* d_ws, size_t ws_size,
                              hipStream_t stream) {
    const float* x  = (const float*)d_in[0];
    const void*  eb = d_in[1];
    const float* W0 = (const float*)d_in[2];
    const float* b0 = (const float*)d_in[3];
    const float* g0 = (const float*)d_in[4];
    const float* be0 = (const float*)d_in[5];
    const float* W1 = (const float*)d_in[6];
    const float* b1 = (const float*)d_in[7];
    const float* g1 = (const float*)d_in[8];
    const float* be1 = (const float*)d_in[9];

    const int N = in_sizes[0] / D;
    const int E = in_sizes[1] / 2;
    const int NBUK = (N + 255) >> 8;
    const int NBLK = (E + CHUNK - 1) / CHUNK;

    auto al = [](size_t v) { return (v + 255) & ~(size_t)255; };
    char* w = (char*)d_ws;
    size_t off = 0;
    int* flag = (int*)(w + off);          off = al(off + 4);
    int* gcur = (int*)(w + off);          off = al(off + 256 * 4);
    int* rbeg = (int*)(w + off);          off = al(off + (size_t)N * 4);
    int* rend = (int*)(w + off);          off = al(off + (size_t)N * 4);
    float* dis = (float*)(w + off);       off = al(off + (size_t)N * 4);
    int* csr_src = (int*)(w + off);       off = al(off + ((size_t)NBUK * BCAPP + 64) * 4);
    unsigned* part = (unsigned*)(w + off); off = al(off + ((size_t)NBUK * BCAP + BCAP) * 4);
    ushort_t* hs = (ushort_t*)(w + off);  off = al(off + ((size_t)N + 1) * D * 2);
    ushort_t* h1b = (ushort_t*)(w + off); off = al(off + (size_t)N * D * 2);
    ushort_t* Wt0 = (ushort_t*)(w + off); off = al(off + 9216 * 2);
    ushort_t* Wt1 = (ushort_t*)(w + off); off = al(off + 9216 * 2);
    float* outf = (float*)d_out;

    const int nbG = (N + 63) / 64;
    const int nbA = (N + 7) / 8;

    k_init<<<73, 256, 0, stream>>>((const unsigned*)eb, flag, gcur, hs, N, NBUK,
                                   W0, W1, Wt0, Wt1);
    k_bfill<<<NBLK, 256, 0, stream>>>(eb, flag, gcur, part, E);
    k_build<<<NBUK, 256, 0, stream>>>(part, gcur, rbeg, rend, csr_src, dis, N);

    // Layer 1: MFMA GEMM (f32 in, converts while staging) -> hs ; agg -> h1b
    k_gemm_mfma<float><<<nbG, 256, 0, stream>>>(x, Wt0, dis, hs, N);
    k_agg_ln<true><<<nbA, 256, 0, stream>>>(hs, rbeg, rend, csr_src, dis,
                                            b0, g0, be0, (void*)h1b, N);
    // Layer 2: MFMA GEMM (bf16 in) -> hs ; agg -> d_out (f32)
    k_gemm_mfma<ushort_t><<<nbG, 256, 0, stream>>>(h1b, Wt1, dis, hs, N);
    k_agg_ln<false><<<nbA, 256, 0, stream>>>(hs, rbeg, rend, csr_src, dis,
                                             b1, g1, be1, (void*)outf, N);
}

// Round 7
// 120.370 us; speedup vs baseline: 2.1052x; 1.0141x over previous
//
#include <hip/hip_runtime.h>
#include <hip/hip_bf16.h>
#include <type_traits>

#define D 96
#define LN_EPS 1e-5f
#define CHUNK 1024        // edges per partition block
#define BCAP 8192         // per-bucket fixed capacity in part[] (mean 4096, +64 sigma)
#define BCAPP (BCAP + 1792) // per-bucket region in csr_src (pad-8 slack = 7*256)

typedef unsigned short ushort_t;
typedef __attribute__((ext_vector_type(8))) short short8;
typedef __attribute__((ext_vector_type(4))) float f32x4;

__device__ __forceinline__ ushort_t f2bf(float f) {
    unsigned u = __float_as_uint(f);
    u += 0x7FFF + ((u >> 16) & 1);          // round-to-nearest-even
    return (ushort_t)(u >> 16);
}
__device__ __forceinline__ float blo(unsigned v) {   // low bf16 -> f32
    return __uint_as_float(v << 16);
}
__device__ __forceinline__ float bhi(unsigned v) {   // high bf16 -> f32
    return __uint_as_float(v & 0xffff0000u);
}

// ---------------------------------------------------------------------------
// Init (block 0): edge dtype detect + gcur = b*BCAP + zero hs sentinel rows.
// Blocks 1..72: W0,W1 (f32 [k][c]) -> Wt0,Wt1 (bf16 transposed [c][k]).
// ---------------------------------------------------------------------------
__global__ __launch_bounds__(256) void k_init(const unsigned* __restrict__ w,
                                              int* __restrict__ flag,
                                              int* __restrict__ gcur,
                                              unsigned* __restrict__ hsA,
                                              unsigned* __restrict__ hsB, int N,
                                              int nbuk,
                                              const float* __restrict__ W0,
                                              const float* __restrict__ W1,
                                              ushort_t* __restrict__ Wt0,
                                              ushort_t* __restrict__ Wt1) {
    int t = threadIdx.x;
    if (blockIdx.x == 0) {
        __shared__ int anynz;
        if (t == 0) anynz = 0;
        __syncthreads();
        if ((t & 1) && w[t] != 0) anynz = 1;
        if (t < nbuk) gcur[t] = t * BCAP;
        if (t < 32) hsA[(size_t)N * 32 + t] = 0;   // sentinel row
        if (t < 16) hsB[(size_t)N * 16 + t] = 0;
        __syncthreads();
        if (t == 0) *flag = (anynz == 0) ? 1 : 0;
    } else {
        int idx = (blockIdx.x - 1) * 256 + t;   // < 18432
        int sel = idx / 9216, i = idx % 9216;
        int c = i / 96, k = i % 96;
        const float* W = sel ? W1 : W0;
        ushort_t* Wt = sel ? Wt1 : Wt0;
        Wt[c * 96 + k] = f2bf(W[k * 96 + c]);
    }
}

__device__ __forceinline__ int load_idx(const void* eb, int is64, long long pos) {
    if (is64) return (int)((const long long*)eb)[pos];
    return ((const int*)eb)[pos];
}

// ---------------------------------------------------------------------------
// Partition edges into fixed-capacity bucket regions (bucket = dst >> 8).
// Duplicated LDS hist/cursors (per wave-pair) halve same-bin serialization.
// ---------------------------------------------------------------------------
__global__ __launch_bounds__(256) void k_bfill(const void* __restrict__ eb,
                                               const int* __restrict__ flag,
                                               int* __restrict__ gcur,
                                               unsigned* __restrict__ part, int E) {
    __shared__ int hist[2][256];
    __shared__ int cur[2][256];
    int t = threadIdx.x;
    int half = t >> 7;
    hist[0][t] = 0; hist[1][t] = 0;
    __syncthreads();
    int is64 = *flag;
    long long base = (long long)blockIdx.x * CHUNK;
    int sv[CHUNK / 256];
    int dv[CHUNK / 256];
    #pragma unroll
    for (int i = 0; i < CHUNK / 256; ++i) {
        long long e = base + t + (long long)i * 256;
        if (e < E) {
            sv[i] = load_idx(eb, is64, e);
            dv[i] = load_idx(eb, is64, (long long)E + e);
            atomicAdd(&hist[half][dv[i] >> 8], 1);
        } else dv[i] = -1;
    }
    __syncthreads();
    int h0 = hist[0][t], tot = h0 + hist[1][t];
    int b0 = 0;
    if (tot > 0) b0 = atomicAdd(&gcur[t], tot);
    cur[0][t] = b0;
    cur[1][t] = b0 + h0;
    __syncthreads();
    #pragma unroll
    for (int i = 0; i < CHUNK / 256; ++i) {
        if (dv[i] >= 0) {
            int b = dv[i] >> 8;
            int pos = atomicAdd(&cur[half][b], 1);
            part[pos] = ((unsigned)sv[i] << 8) | (unsigned)(dv[i] & 255);
        }
    }
}

// ---------------------------------------------------------------------------
// Per-bucket CSR finalize, per-node padding to multiple of 8 (sentinel = N).
// Bucket b: part region [b*BCAP, gcur[b]); csr region starts at b*BCAPP.
// rr[node] = (rbeg, rend) packed.
// ---------------------------------------------------------------------------
__global__ __launch_bounds__(256) void k_build(const unsigned* __restrict__ part,
                                               const int* __restrict__ gcur,
                                               int2* __restrict__ rr,
                                               int* __restrict__ csr_src,
                                               float* __restrict__ dis,
                                               int N) {
    __shared__ int bins[2][256];
    __shared__ int cur[2][256];
    __shared__ int sh[256];
    int t = threadIdx.x;
    int b = blockIdx.x;
    int half = t >> 7;
    int beg = b * BCAP, end = gcur[b];
    bins[0][t] = 0; bins[1][t] = 0;
    __syncthreads();
    for (int i = beg + t; i < end; i += 256)
        atomicAdd(&bins[half][part[i] & 255u], 1);
    __syncthreads();
    int d0 = bins[0][t];
    int deg = d0 + bins[1][t];
    int pdeg = (deg + 7) & ~7;
    sh[t] = pdeg;
    __syncthreads();
    for (int off = 1; off < 256; off <<= 1) {
        int x = (t >= off) ? sh[t - off] : 0;
        __syncthreads();
        sh[t] += x;
        __syncthreads();
    }
    int mybeg = b * BCAPP + (sh[t] - pdeg);
    int node = b * 256 + t;
    if (node < N) {
        rr[node] = make_int2(mybeg, mybeg + pdeg);
        dis[node] = rsqrtf((float)(deg + 1));
    }
    cur[0][t] = mybeg;
    cur[1][t] = mybeg + d0;
    __syncthreads();
    for (int i = beg + t; i < end; i += 256) {
        unsigned p = part[i];
        int pos = atomicAdd(&cur[half][p & 255u], 1);
        csr_src[pos] = (int)(p >> 8);
    }
    for (int k = deg; k < pdeg; ++k) csr_src[mybeg + k] = N;  // sentinels
}

// ---------------------------------------------------------------------------
// MFMA GEMM: (HsA,HsB)[row] = bf16( dis[row] * (A[N,96] @ W[96,96]) ).
// A: f32 contiguous (layer 1, converted while staging) or split bf16
// (A0=[N][64], A1=[N][32], layer 2). Wt bf16 transposed. 64 rows/block,
// 4 waves, 16 rows/wave. mfma_f32_16x16x32_bf16, m89-verified C/D layout.
// LDS rows padded to 104 elems (208B) -> 2-way conflicts only (free).
// ---------------------------------------------------------------------------
template<typename T>
__global__ __launch_bounds__(256) void k_gemm_mfma(const T* __restrict__ A0,
                                                   const T* __restrict__ A1,
                                                   const ushort_t* __restrict__ Wt,
                                                   const float* __restrict__ dis,
                                                   ushort_t* __restrict__ HsA,
                                                   ushort_t* __restrict__ HsB, int N) {
    __shared__ ushort_t As[64][104];
    __shared__ ushort_t Bs[96][104];
    int t = threadIdx.x;
    int row0 = blockIdx.x * 64;

    if constexpr (std::is_same<T, float>::value) {
        const float4* X4 = (const float4*)A0;
        #pragma unroll
        for (int i = 0; i < 6; ++i) {             // 64x24 float4 = 1536 chunks
            int idx = t + i * 256;
            int r = idx / 24, c4 = idx % 24;
            float4 v = make_float4(0.f, 0.f, 0.f, 0.f);
            if (row0 + r < N) v = X4[(size_t)(row0 + r) * 24 + c4];
            ushort4 o;
            o.x = f2bf(v.x); o.y = f2bf(v.y); o.z = f2bf(v.z); o.w = f2bf(v.w);
            *(ushort4*)&As[r][c4 * 4] = o;
        }
    } else {
        #pragma unroll
        for (int i = 0; i < 3; ++i) {             // 64x12 short8 = 768 chunks
            int idx = t + i * 256;
            int r = idx / 12, c8 = idx % 12;
            short8 v = {0, 0, 0, 0, 0, 0, 0, 0};
            if (row0 + r < N) {
                if (c8 < 8) v = *(const short8*)(A0 + (size_t)(row0 + r) * 64 + c8 * 8);
                else        v = *(const short8*)(A1 + (size_t)(row0 + r) * 32 + (c8 - 8) * 8);
            }
            *(short8*)&As[r][c8 * 8] = v;
        }
    }
    #pragma unroll
    for (int i = 0; i < 5; ++i) {                 // 96x12 short8 = 1152 chunks
        int idx = t + i * 256;
        if (idx < 1152) {
            int r = idx / 12, c8 = idx % 12;
            *(short8*)&Bs[r][c8 * 8] = *(const short8*)(Wt + r * 96 + c8 * 8);
        }
    }
    __syncthreads();

    int w = t >> 6, l = t & 63;
    int lr = l & 15, lq = l >> 4;
    f32x4 acc[6];
    #pragma unroll
    for (int c = 0; c < 6; ++c) acc[c] = (f32x4){0.f, 0.f, 0.f, 0.f};

    #pragma unroll
    for (int q = 0; q < 3; ++q) {
        short8 af = *(const short8*)&As[w * 16 + lr][q * 32 + lq * 8];
        #pragma unroll
        for (int c = 0; c < 6; ++c) {
            short8 bf = *(const short8*)&Bs[c * 16 + lr][q * 32 + lq * 8];
            acc[c] = __builtin_amdgcn_mfma_f32_16x16x32_bf16(af, bf, acc[c], 0, 0, 0);
        }
    }

    int rbase = row0 + w * 16 + lq * 4;
    #pragma unroll
    for (int r = 0; r < 4; ++r) {
        int gr = rbase + r;
        if (gr < N) {
            float dr = dis[gr];
            ushort_t* oA = HsA + (size_t)gr * 64 + lr;
            ushort_t* oB = HsB + (size_t)gr * 32 + lr;
            #pragma unroll
            for (int c = 0; c < 4; ++c) oA[c * 16] = f2bf(dr * acc[c][r]);
            #pragma unroll
            for (int c = 4; c < 6; ++c) oB[(c - 4) * 16] = f2bf(dr * acc[c][r]);
        }
    }
}

// ---------------------------------------------------------------------------
// Fused aggregate + bias + tanh + LayerNorm + affine; split-hs gathers.
// 32-lane group per node. Lane l owns features {2l,2l+1} (hsA). hsB
// (features 64-95) is gathered two-edges-per-load: lanes 0-15 edge j,
// lanes 16-31 edge j+1, folded by shfl_xor(16) before the epilogue.
// Edge runs padded to x8 with sentinel row N (zeros); branch-free bursts.
// ---------------------------------------------------------------------------
template<bool BF16OUT>
__global__ __launch_bounds__(256) void k_agg_ln(const unsigned* __restrict__ hA32,
                                                const unsigned* __restrict__ hB32,
                                                const int2* __restrict__ rr,
                                                const int* __restrict__ csr_src,
                                                const float* __restrict__ dis,
                                                const float* __restrict__ b,
                                                const float* __restrict__ g,
                                                const float* __restrict__ be,
                                                void* __restrict__ outA,
                                                void* __restrict__ outB, int N) {
    int node = blockIdx.x * 8 + (threadIdx.x >> 5);
    int lane = threadIdx.x & 31;
    if (node >= N) return;

    float a0, a1, c0 = 0.f, c1 = 0.f;
    {
        unsigned v = hA32[(size_t)node * 32 + lane];
        a0 = blo(v); a1 = bhi(v);
        if (lane < 16) {
            unsigned u = hB32[(size_t)node * 16 + lane];
            c0 = blo(u); c1 = bhi(u);
        }
    }

    int2 r = rr[node];
    int beg = r.x, end = r.y;
    int lsel = lane >> 4;      // 0 for lanes 0-15, 1 for 16-31
    int lb = lane & 15;
    for (int cb = beg; cb < end; cb += 32) {
        int m = min(32, end - cb);
        int e = cb + lane;
        int sreg = (e < end) ? csr_src[e] : (int)N;
        for (int j = 0; j < m; j += 8) {
            int s0 = __shfl(sreg, j, 32);
            int s1 = __shfl(sreg, j + 1, 32);
            int s2 = __shfl(sreg, j + 2, 32);
            int s3 = __shfl(sreg, j + 3, 32);
            int s4 = __shfl(sreg, j + 4, 32);
            int s5 = __shfl(sreg, j + 5, 32);
            int s6 = __shfl(sreg, j + 6, 32);
            int s7 = __shfl(sreg, j + 7, 32);
            int p0 = __shfl(sreg, j + lsel, 32);
            int p1 = __shfl(sreg, j + 2 + lsel, 32);
            int p2 = __shfl(sreg, j + 4 + lsel, 32);
            int p3 = __shfl(sreg, j + 6 + lsel, 32);
            unsigned v0 = hA32[s0 * 32 + lane];
            unsigned v1 = hA32[s1 * 32 + lane];
            unsigned v2 = hA32[s2 * 32 + lane];
            unsigned v3 = hA32[s3 * 32 + lane];
            unsigned v4 = hA32[s4 * 32 + lane];
            unsigned v5 = hA32[s5 * 32 + lane];
            unsigned v6 = hA32[s6 * 32 + lane];
            unsigned v7 = hA32[s7 * 32 + lane];
            unsigned w0 = hB32[p0 * 16 + lb];
            unsigned w1 = hB32[p1 * 16 + lb];
            unsigned w2 = hB32[p2 * 16 + lb];
            unsigned w3 = hB32[p3 * 16 + lb];
            a0 += blo(v0) + blo(v1) + blo(v2) + blo(v3)
                + blo(v4) + blo(v5) + blo(v6) + blo(v7);
            a1 += bhi(v0) + bhi(v1) + bhi(v2) + bhi(v3)
                + bhi(v4) + bhi(v5) + bhi(v6) + bhi(v7);
            c0 += blo(w0) + blo(w1) + blo(w2) + blo(w3);
            c1 += bhi(w0) + bhi(w1) + bhi(w2) + bhi(w3);
        }
    }

    // fold dual-edge hB accumulators (both halves end with the total)
    c0 += __shfl_xor(c0, 16, 32);
    c1 += __shfl_xor(c1, 16, 32);

    float dn = dis[node];
    float2 b01 = ((const float2*)b)[lane];
    a0 = tanhf(fmaf(dn, a0, b01.x));
    a1 = tanhf(fmaf(dn, a1, b01.y));
    float s1 = a0 + a1;
    float s2 = a0 * a0 + a1 * a1;
    float a2 = 0.f, a3 = 0.f;
    if (lane < 16) {
        float2 b23 = ((const float2*)b)[32 + lane];
        a2 = tanhf(fmaf(dn, c0, b23.x));
        a3 = tanhf(fmaf(dn, c1, b23.y));
        s1 += a2 + a3;
        s2 += a2 * a2 + a3 * a3;
    }
    #pragma unroll
    for (int off = 16; off >= 1; off >>= 1) {
        s1 += __shfl_xor(s1, off, 32);
        s2 += __shfl_xor(s2, off, 32);
    }
    float mu = s1 * (1.f / 96.f);
    float var = s2 * (1.f / 96.f) - mu * mu;
    float inv = rsqrtf(var + LN_EPS);

    float2 g01 = ((const float2*)g)[lane];
    float2 e01 = ((const float2*)be)[lane];
    float r0 = (a0 - mu) * inv * g01.x + e01.x;
    float r1 = (a1 - mu) * inv * g01.y + e01.y;
    if (BF16OUT) {
        ((unsigned*)outA)[(size_t)node * 32 + lane] =
            ((unsigned)f2bf(r1) << 16) | (unsigned)f2bf(r0);
        if (lane < 16) {
            float2 g23 = ((const float2*)g)[32 + lane];
            float2 e23 = ((const float2*)be)[32 + lane];
            float r2 = (a2 - mu) * inv * g23.x + e23.x;
            float r3 = (a3 - mu) * inv * g23.y + e23.y;
            ((unsigned*)outB)[(size_t)node * 16 + lane] =
                ((unsigned)f2bf(r3) << 16) | (unsigned)f2bf(r2);
        }
    } else {
        float2* o2 = (float2*)((float*)outA + (size_t)node * D);
        o2[lane] = make_float2(r0, r1);
        if (lane < 16) {
            float2 g23 = ((const float2*)g)[32 + lane];
            float2 e23 = ((const float2*)be)[32 + lane];
            o2[32 + lane] = make_float2((a2 - mu) * inv * g23.x + e23.x,
                                        (a3 - mu) * inv * g23.y + e23.y);
        }
    }
}

// ---------------------------------------------------------------------------
extern "C" void kernel_launch(void* const* d_in, const int* in_sizes, int n_in,
                              void* d_out, int out_size, void* d_ws, size_t ws_size,
                              hipStream_t stream) {
    const float* x  = (const float*)d_in[0];
    const void*  eb = d_in[1];
    const float* W0 = (const float*)d_in[2];
    const float* b0 = (const float*)d_in[3];
    const float* g0 = (const float*)d_in[4];
    const float* be0 = (const float*)d_in[5];
    const float* W1 = (const float*)d_in[6];
    const float* b1 = (const float*)d_in[7];
    const float* g1 = (const float*)d_in[8];
    const float* be1 = (const float*)d_in[9];

    const int N = in_sizes[0] / D;
    const int E = in_sizes[1] / 2;
    const int NBUK = (N + 255) >> 8;
    const int NBLK = (E + CHUNK - 1) / CHUNK;

    auto al = [](size_t v) { return (v + 255) & ~(size_t)255; };
    char* w = (char*)d_ws;
    size_t off = 0;
    int* flag = (int*)(w + off);          off = al(off + 4);
    int* gcur = (int*)(w + off);          off = al(off + 256 * 4);
    int2* rr = (int2*)(w + off);          off = al(off + (size_t)N * 8);
    float* dis = (float*)(w + off);       off = al(off + (size_t)N * 4);
    int* csr_src = (int*)(w + off);       off = al(off + ((size_t)NBUK * BCAPP + 64) * 4);
    unsigned* part = (unsigned*)(w + off); off = al(off + ((size_t)NBUK * BCAP + BCAP) * 4);
    unsigned* hsA = (unsigned*)(w + off); off = al(off + ((size_t)N + 1) * 128);
    unsigned* hsB = (unsigned*)(w + off); off = al(off + ((size_t)N + 1) * 64);
    ushort_t* h1A = (ushort_t*)(w + off); off = al(off + (size_t)N * 128);
    ushort_t* h1B = (ushort_t*)(w + off); off = al(off + (size_t)N * 64);
    ushort_t* Wt0 = (ushort_t*)(w + off); off = al(off + 9216 * 2);
    ushort_t* Wt1 = (ushort_t*)(w + off); off = al(off + 9216 * 2);
    float* outf = (float*)d_out;

    const int nbG = (N + 63) / 64;
    const int nbA = (N + 7) / 8;

    k_init<<<73, 256, 0, stream>>>((const unsigned*)eb, flag, gcur, hsA, hsB, N,
                                   NBUK, W0, W1, Wt0, Wt1);
    k_bfill<<<NBLK, 256, 0, stream>>>(eb, flag, gcur, part, E);
    k_build<<<NBUK, 256, 0, stream>>>(part, gcur, rr, csr_src, dis, N);

    // Layer 1: MFMA GEMM (f32 in, converts while staging) -> hsA/hsB ; agg -> h1A/h1B
    k_gemm_mfma<float><<<nbG, 256, 0, stream>>>(x, (const float*)nullptr, Wt0, dis,
                                                (ushort_t*)hsA, (ushort_t*)hsB, N);
    k_agg_ln<true><<<nbA, 256, 0, stream>>>(hsA, hsB, rr, csr_src, dis,
                                            b0, g0, be0, (void*)h1A, (void*)h1B, N);
    // Layer 2: MFMA GEMM (split bf16 in) -> hsA/hsB ; agg -> d_out (f32)
    k_gemm_mfma<ushort_t><<<nbG, 256, 0, stream>>>(h1A, h1B, Wt1, dis,
                                                   (ushort_t*)hsA, (ushort_t*)hsB, N);
    k_agg_ln<false><<<nbA, 256, 0, stream>>>(hsA, hsB, rr, csr_src, dis,
                                             b1, g1, be1, (void*)outf, nullptr, N);
}